// Round 2
// 511.216 us; speedup vs baseline: 1.0402x; 1.0402x over previous
//
#include <hip/hip_runtime.h>
#include <math.h>

// Problem constants: B=2, T=2048, E=1024, H=16, D=64; M = B*T = 4096
#define MM   4096
#define TT   2048
#define HH   16

typedef __bf16 bf16x8 __attribute__((ext_vector_type(8)));
typedef float f32x4 __attribute__((ext_vector_type(4)));

// async global->LDS, 16B per lane; LDS dest = wave-uniform base + lane*16
__device__ __forceinline__ void g2l16(const void* g, void* l) {
    __builtin_amdgcn_global_load_lds(
        (__attribute__((address_space(1))) void*)g,
        (__attribute__((address_space(3))) void*)l, 16, 0, 0);
}

// ---- raw transcendentals (guarded; libm fallback). Without -ffast-math the
// libm versions lower to multi-instruction OCML guard sequences — 3-4x cost.
#if __has_builtin(__builtin_amdgcn_exp2f)
__device__ __forceinline__ float fexp2(float x) { return __builtin_amdgcn_exp2f(x); }
#else
__device__ __forceinline__ float fexp2(float x) { return exp2f(x); }
#endif
#if __has_builtin(__builtin_amdgcn_logf)
__device__ __forceinline__ float flog2(float x) { return __builtin_amdgcn_logf(x); }
#else
__device__ __forceinline__ float flog2(float x) { return log2f(x); }
#endif
#if __has_builtin(__builtin_amdgcn_sqrtf)
__device__ __forceinline__ float fsqrt_(float x) { return __builtin_amdgcn_sqrtf(x); }
#else
__device__ __forceinline__ float fsqrt_(float x) { return sqrtf(x); }
#endif
#if __has_builtin(__builtin_amdgcn_rcpf)
__device__ __forceinline__ float frcp_(float x) { return __builtin_amdgcn_rcpf(x); }
#else
__device__ __forceinline__ float frcp_(float x) { return 1.0f / x; }
#endif
#if __has_builtin(__builtin_amdgcn_rsqf)
__device__ __forceinline__ float frsq_(float x) { return __builtin_amdgcn_rsqf(x); }
#else
__device__ __forceinline__ float frsq_(float x) { return rsqrtf(x); }
#endif

// ---------------------------------------------------------------- reductions
__device__ __forceinline__ float blockSum256(float v, volatile float* sb) {
    int lane = threadIdx.x & 63, w = threadIdx.x >> 6;
#pragma unroll
    for (int o = 32; o; o >>= 1) v += __shfl_xor(v, o);
    if (lane == 0) sb[w] = v;
    __syncthreads();
    v = sb[0] + sb[1] + sb[2] + sb[3];
    __syncthreads();
    return v;
}

// ---------------------------------------------------------------- block_norm -> bf16 (ldo-wide, zero pad)
__global__ __launch_bounds__(256) void block_norm_bf_k(
    const float* __restrict__ in, int ld,
    __bf16* __restrict__ out, int ldo,
    const float* __restrict__ lw, const float* __restrict__ lb,
    const float* __restrict__ curv)
{
    int row = blockIdx.x;
    const float* x = in + (size_t)row * ld;
    __bf16* o = out + (size_t)row * ldo;
    __shared__ float sb[4];
    int tid = threadIdx.x;
    float v[4]; float s1 = 0.f, s2 = 0.f;
#pragma unroll
    for (int r = 0; r < 4; r++) {
        float t = x[tid + 256 * r];
        v[r] = t; s1 += t; s2 += t * t;
    }
    s1 = blockSum256(s1, sb);
    s2 = blockSum256(s2, sb);
    float mean = s1 * (1.f / 1024.f);
    float var  = s2 * (1.f / 1024.f) - mean * mean;
    float rs = rsqrtf(var + 1e-5f);
    float y[4]; float ssq = 0.f;
#pragma unroll
    for (int r = 0; r < 4; r++) {
        int i = tid + 256 * r;
        float t = (v[r] - mean) * rs * lw[i] + lb[i];
        y[r] = t; ssq += t * t;
    }
    ssq = blockSum256(ssq, sb);
#pragma unroll
    for (int r = 0; r < 4; r++) o[1 + tid + 256 * r] = (__bf16)y[r];
    if (tid == 0) o[0] = (__bf16)sqrtf(expf(*curv) + ssq);
    if (tid < ldo - 1025) o[1025 + tid] = (__bf16)0.f;   // zero pad cols 1025..ldo-1
}

// ---------------------------------------------------------------- row x0 (fp32, final output)
__global__ __launch_bounds__(256) void row_x0_k(
    float* __restrict__ buf, int stride, int n, const float* __restrict__ curv)
{
    int row = blockIdx.x;
    float* base = buf + (size_t)row * stride;
    __shared__ float sb[4];
    float s = 0.f;
    for (int i = threadIdx.x; i < n; i += 256) { float t = base[1 + i]; s += t * t; }
    s = blockSum256(s, sb);
    if (threadIdx.x == 0) base[0] = sqrtf(expf(*curv) + s);
}

// ---------------------------------------------------------------- h tail (3 ragged cols) + x0 + pad (stride 4224)
// The 256^2 expand GEMM covers cols 1..4096 with an exact 16x16 grid (no
// straggler wave); this kernel computes the 3 remaining cols (dot with meT
// rows 4096..4098, K=1088, L2-resident), applies bias+gelu, and fuses the
// x0 sum-of-squares + pad-zeroing it replaces.
__global__ __launch_bounds__(256) void row_x0_tail_k(
    __bf16* __restrict__ h,
    const __bf16* __restrict__ ln,      // ln2, stride 1088 (zero-padded past 1025)
    const __bf16* __restrict__ Bt,      // meT, stride 1088
    const float* __restrict__ bias,     // b_me (4099)
    const float* __restrict__ curv)
{
    int row = blockIdx.x;
    __bf16* base = h + (size_t)row * 4224;
    const __bf16* lnr = ln + (size_t)row * 1088;
    const __bf16* B0 = Bt + (size_t)4096 * 1088;
    const __bf16* B1 = Bt + (size_t)4097 * 1088;
    const __bf16* B2 = Bt + (size_t)4098 * 1088;
    __shared__ float sb[4];
    float d0 = 0.f, d1 = 0.f, d2 = 0.f;
    for (int i = threadIdx.x; i < 1088; i += 256) {
        float a = (float)lnr[i];
        d0 += a * (float)B0[i];
        d1 += a * (float)B1[i];
        d2 += a * (float)B2[i];
    }
    d0 = blockSum256(d0, sb);
    d1 = blockSum256(d1, sb);
    d2 = blockSum256(d2, sb);
    float t3[3] = {d0 + bias[4096], d1 + bias[4097], d2 + bias[4098]};
    float ssq_t = 0.f;
#pragma unroll
    for (int j = 0; j < 3; j++) {
        float v = t3[j];
        v = 0.5f * v * (1.f + erff(v * 0.70710678118654752f));
        t3[j] = v; ssq_t += v * v;
    }
    if (threadIdx.x == 0) {
        base[1 + 4096] = (__bf16)t3[0];
        base[1 + 4097] = (__bf16)t3[1];
        base[1 + 4098] = (__bf16)t3[2];
    }
    float s = 0.f;
    for (int i = threadIdx.x; i < 4096; i += 256) { float t = (float)base[1 + i]; s += t * t; }
    s = blockSum256(s, sb) + ssq_t;
    if (threadIdx.x == 0) base[0] = (__bf16)sqrtf(expf(*curv) + s);
    if (threadIdx.x < 124) base[4100 + threadIdx.x] = (__bf16)0.f;  // zero pad 4100..4223
}

// ---------------------------------------------------------------- weight convert + transpose
__global__ __launch_bounds__(256) void wt_k(
    const float* __restrict__ W, int K, int N,
    __bf16* __restrict__ Wt, int Kp)
{
    __shared__ float s[32][33];
    int tx = threadIdx.x & 31, ty = threadIdx.x >> 5;    // 32 x 8
    int k0 = blockIdx.x * 32, n0 = blockIdx.y * 32;
#pragma unroll
    for (int r = 0; r < 4; r++) {
        int k = k0 + ty + 8 * r, n = n0 + tx;
        s[ty + 8 * r][tx] = (k < K && n < N) ? W[(size_t)k * N + n] : 0.f;
    }
    __syncthreads();
#pragma unroll
    for (int r = 0; r < 4; r++) {
        int n = n0 + ty + 8 * r, k = k0 + tx;
        if (n < N) Wt[(size_t)n * Kp + k] = (__bf16)s[tx][ty + 8 * r];
    }
}

// ---------------------------------------------------------------- bf16 MFMA GEMM 256x256, BK=64, 8-phase
// 512 thr (8 waves, 2M x 4N), per-wave C = 128x64 (acc[8][4]).
// LDS 128 KiB: A/B double-buffered at K-tile granularity. XOR-swizzled LDS
// (pre-swizzled global source + swizzled ds_read, rule-21 both-sides).
// Per K-tile: 4 phases {ds_read subtile; barrier; setprio; 16 MFMA; setprio;
// barrier}; next tile's 8 g2l16 issued at phase 1 so the vmcnt(0)+lgkmcnt(0)
// boundary wait lands ~4 MFMA-phases after issue (latency hidden, no
// per-phase drain — T3/T4/T5 from the 8-phase template).
template<bool BIAS, bool GELU, bool OUTBF>
__global__ __launch_bounds__(512, 2) void mgemm256_k(
    const __bf16* __restrict__ A, int lda,
    const __bf16* __restrict__ Bt, int ldb, int NB,   // NB = valid rows of Bt (row clamp)
    const float* __restrict__ bias,
    void* __restrict__ Cout, int ldc,
    int N, int Kp)                                     // Kp multiple of 64
{
    __shared__ __bf16 sAB[65536];   // [A db0 |A db1 |B db0 |B db1] x 16384 elems
    const int tid = threadIdx.x;
    const int w = tid >> 6, lane = tid & 63;
    const int wm = w >> 2, wn = w & 3;
    const int lr = lane & 15, lq = lane >> 4;
    const int m0 = blockIdx.y * 256, n0 = blockIdx.x * 256;

    // staging: 4 chunks of 64 rows x 64 K each (8 KB); thread t covers row rr,
    // 16B slot (t&7), source col pre-XOR-swizzled so linear LDS dest + swizzled
    // ds_read see consistent data.
    const int rr  = tid >> 3;
    const int csw = ((tid & 7) ^ (rr & 7)) << 3;   // elems
    const __bf16* gA[4]; const __bf16* gB[4];
#pragma unroll
    for (int c = 0; c < 4; c++) {
        gA[c] = A + (size_t)(m0 + c * 64 + rr) * lda + csw;
        int rb = n0 + c * 64 + rr; rb = (rb < NB) ? rb : (NB - 1);
        gB[c] = Bt + (size_t)rb * ldb + csw;
    }
    __bf16* lA = sAB + (w << 9);            // + db*16384 + c*4096
    __bf16* lB = sAB + 32768 + (w << 9);

    // swizzled fragment read offsets (elems): (ks*32 + lq*8) ^ ((lr&7)<<3)
    const int off0 = (lq * 8) ^ ((lr & 7) << 3);
    const int off1 = off0 ^ 32;
    const int arow = wm * 128 + lr;
    const int brow = wn * 64 + lr;

    f32x4 zero = {0.f, 0.f, 0.f, 0.f};
    f32x4 acc[8][4];
#pragma unroll
    for (int i = 0; i < 8; i++)
#pragma unroll
        for (int j = 0; j < 4; j++) acc[i][j] = zero;

    // prologue: stage K-tile 0 -> db0
#pragma unroll
    for (int c = 0; c < 4; c++) {
        g2l16(gA[c], lA + c * 4096);
        g2l16(gB[c], lB + c * 4096);
    }
    asm volatile("s_waitcnt vmcnt(0)" ::: "memory");
    __builtin_amdgcn_s_barrier();

    const int NT = Kp >> 6;
    for (int kt = 0; kt < NT; ++kt) {
        const int cur = kt & 1;
        const __bf16* pA = sAB + cur * 16384;
        const __bf16* pB = sAB + 32768 + cur * 16384;
        bf16x8 af[4][2], bfr[4][2];

        // ---- phase 1: issue next-tile stage early; read A half0 + B[0..1]; MFMA q00
        if (kt + 1 < NT) {
            const int ko = (kt + 1) << 6;
            __bf16* dA = lA + (cur ^ 1) * 16384;
            __bf16* dB = lB + (cur ^ 1) * 16384;
#pragma unroll
            for (int c = 0; c < 4; c++) {
                g2l16(gA[c] + ko, dA + c * 4096);
                g2l16(gB[c] + ko, dB + c * 4096);
            }
        }
#pragma unroll
        for (int i = 0; i < 4; i++) {
            const __bf16* r = pA + (arow + i * 16) * 64;
            af[i][0] = *(const bf16x8*)(r + off0);
            af[i][1] = *(const bf16x8*)(r + off1);
        }
#pragma unroll
        for (int j = 0; j < 2; j++) {
            const __bf16* r = pB + (brow + j * 16) * 64;
            bfr[j][0] = *(const bf16x8*)(r + off0);
            bfr[j][1] = *(const bf16x8*)(r + off1);
        }
        __builtin_amdgcn_s_barrier();
        __builtin_amdgcn_s_setprio(1);
#pragma unroll
        for (int ks = 0; ks < 2; ks++)
#pragma unroll
            for (int i = 0; i < 4; i++)
#pragma unroll
                for (int j = 0; j < 2; j++)
                    acc[i][j] = __builtin_amdgcn_mfma_f32_16x16x32_bf16(af[i][ks], bfr[j][ks], acc[i][j], 0, 0, 0);
        __builtin_amdgcn_s_setprio(0);
        __builtin_amdgcn_s_barrier();

        // ---- phase 2: read B[2..3]; MFMA q01
#pragma unroll
        for (int j = 2; j < 4; j++) {
            const __bf16* r = pB + (brow + j * 16) * 64;
            bfr[j][0] = *(const bf16x8*)(r + off0);
            bfr[j][1] = *(const bf16x8*)(r + off1);
        }
        __builtin_amdgcn_s_barrier();
        __builtin_amdgcn_s_setprio(1);
#pragma unroll
        for (int ks = 0; ks < 2; ks++)
#pragma unroll
            for (int i = 0; i < 4; i++)
#pragma unroll
                for (int j = 2; j < 4; j++)
                    acc[i][j] = __builtin_amdgcn_mfma_f32_16x16x32_bf16(af[i][ks], bfr[j][ks], acc[i][j], 0, 0, 0);
        __builtin_amdgcn_s_setprio(0);
        __builtin_amdgcn_s_barrier();

        // ---- phase 3: read A half1 (reuse af regs); MFMA q10
#pragma unroll
        for (int i = 0; i < 4; i++) {
            const __bf16* r = pA + (arow + 64 + i * 16) * 64;
            af[i][0] = *(const bf16x8*)(r + off0);
            af[i][1] = *(const bf16x8*)(r + off1);
        }
        __builtin_amdgcn_s_barrier();
        __builtin_amdgcn_s_setprio(1);
#pragma unroll
        for (int ks = 0; ks < 2; ks++)
#pragma unroll
            for (int i = 0; i < 4; i++)
#pragma unroll
                for (int j = 0; j < 2; j++)
                    acc[4 + i][j] = __builtin_amdgcn_mfma_f32_16x16x32_bf16(af[i][ks], bfr[j][ks], acc[4 + i][j], 0, 0, 0);
        __builtin_amdgcn_s_setprio(0);
        __builtin_amdgcn_s_barrier();

        // ---- phase 4: MFMA q11; tile boundary (the ONLY vmcnt wait per tile)
        __builtin_amdgcn_s_setprio(1);
#pragma unroll
        for (int ks = 0; ks < 2; ks++)
#pragma unroll
            for (int i = 0; i < 4; i++)
#pragma unroll
                for (int j = 2; j < 4; j++)
                    acc[4 + i][j] = __builtin_amdgcn_mfma_f32_16x16x32_bf16(af[i][ks], bfr[j][ks], acc[4 + i][j], 0, 0, 0);
        __builtin_amdgcn_s_setprio(0);
        asm volatile("s_waitcnt vmcnt(0) lgkmcnt(0)" ::: "memory");
        __builtin_amdgcn_s_barrier();
    }

    // ---- epilogue
#pragma unroll
    for (int j = 0; j < 4; j++) {
        const int n = n0 + wn * 64 + j * 16 + lr;
        if (n < N) {
            const float bv = BIAS ? bias[n] : 0.f;
#pragma unroll
            for (int i = 0; i < 8; i++) {
#pragma unroll
                for (int r = 0; r < 4; r++) {
                    const int m = m0 + wm * 128 + i * 16 + lq * 4 + r;
                    float v = acc[i][j][r] + bv;
                    if (GELU) v = 0.5f * v * (1.f + erff(v * 0.70710678118654752f));
                    if (OUTBF) ((__bf16*)Cout)[(size_t)m * ldc + n] = (__bf16)v;
                    else       ((float*)Cout)[(size_t)m * ldc + n] = v;
                }
            }
        }
    }
}

// ---------------------------------------------------------------- bf16 MFMA GEMM 128x64 (2 blocks/CU for N=1024)
template<bool BIAS, bool GELU, bool SKIP>
__global__ __launch_bounds__(256) void mgemm64_k(
    const __bf16* __restrict__ A, int lda,
    const __bf16* __restrict__ Bt, int ldb,
    const float* __restrict__ bias,
    const float* __restrict__ skip, int ldskip,
    float* __restrict__ Cout, int ldc,
    int N, int Kp)
{
    __shared__ __bf16 sA[128 * 32];
    __shared__ __bf16 sB[64 * 32];
    int tid = threadIdx.x;
    int w = tid >> 6, lane = tid & 63;
    int m0 = blockIdx.y * 128, n0 = blockIdx.x * 64;
    const __bf16* Ab = A + (size_t)m0 * lda;
    const __bf16* Bb = Bt + (size_t)n0 * ldb;

    f32x4 zero = {0.f, 0.f, 0.f, 0.f};
    f32x4 acc[4][2];
#pragma unroll
    for (int i = 0; i < 4; i++) { acc[i][0] = zero; acc[i][1] = zero; }

    int mw = (w & 1) * 64, nw = (w >> 1) * 32;
    int lr = lane & 15, lq = lane >> 4;
    int fko = lq * 8;

    int rA = tid >> 2, kkA = (tid & 3) * 8;
    __bf16* lA1 = &sA[(size_t)(w * 64) * 8];
    __bf16* lA2 = &sA[(size_t)(256 + w * 64) * 8];
    __bf16* lB  = &sB[(size_t)(w * 64) * 8];

    for (int k0 = 0; k0 < Kp; k0 += 32) {
        g2l16(Ab + (size_t)rA * lda + k0 + kkA, lA1);
        g2l16(Ab + (size_t)(rA + 64) * lda + k0 + kkA, lA2);
        g2l16(Bb + (size_t)rA * ldb + k0 + kkA, lB);
        __syncthreads();
        bf16x8 af[4], bf[2];
#pragma unroll
        for (int i = 0; i < 4; i++) af[i] = *(const bf16x8*)&sA[(mw + i * 16 + lr) * 32 + fko];
#pragma unroll
        for (int j = 0; j < 2; j++) bf[j] = *(const bf16x8*)&sB[(nw + j * 16 + lr) * 32 + fko];
#pragma unroll
        for (int i = 0; i < 4; i++)
#pragma unroll
            for (int j = 0; j < 2; j++)
                acc[i][j] = __builtin_amdgcn_mfma_f32_16x16x32_bf16(af[i], bf[j], acc[i][j], 0, 0, 0);
        __syncthreads();
    }

#pragma unroll
    for (int j = 0; j < 2; j++) {
        int n = n0 + nw + j * 16 + lr;
        if (n < N) {
            float bv = BIAS ? bias[n] : 0.f;
#pragma unroll
            for (int i = 0; i < 4; i++) {
#pragma unroll
                for (int r = 0; r < 4; r++) {
                    int m = m0 + mw + i * 16 + lq * 4 + r;
                    float v = acc[i][j][r] + bv;
                    if (GELU) v = 0.5f * v * (1.f + erff(v * 0.70710678118654752f));
                    if (SKIP) v += skip[(size_t)m * ldskip + n];
                    Cout[(size_t)m * ldc + n] = v;
                }
            }
        }
    }
}

// ---------------------------------------------------------------- RoPE in-place(q) + Kb bf16 + q/k norms
__global__ __launch_bounds__(256) void rope_k(
    float* __restrict__ QKV, const float* __restrict__ curv,
    float* __restrict__ qt, float* __restrict__ kt,
    __bf16* __restrict__ Kb, __bf16* __restrict__ Obf)
{
    int row = blockIdx.x;              // b*T + t
    int b = row >> 11, t = row & (TT - 1);
    int wv = threadIdx.x >> 6, d = threadIdx.x & 63;
    int j = d & 31;
    float fr = (float)t * powf(10000.0f, -(float)(2 * j) / 64.0f);
    float cv = cosf(fr), sv = sinf(fr);
    float sgn = (d < 32) ? sv : -sv;
    for (int h = wv; h < HH; h += 4) {
        float Kh = expf(curv[h]);
        float* base = QKV + (size_t)row * 3072 + h * 64;
        float q = base[d], k = base[1024 + d];
        float qp = __shfl_xor(q, 32);
        float kp = __shfl_xor(k, 32);
        float qr = q * cv + qp * sgn;
        float kr = k * cv + kp * sgn;
        base[d] = qr;                         // q roped in place (fp32 for hi/lo split)
        size_t oidx = ((size_t)(b * HH + h) * TT + t);
        Kb[oidx * 64 + d] = (__bf16)kr;       // roped k, bf16 head-major
        float sq = qr * qr, sk = kr * kr;
#pragma unroll
        for (int o = 32; o; o >>= 1) {
            sq += __shfl_xor(sq, o);
            sk += __shfl_xor(sk, o);
        }
        if (d == 0) {
            qt[oidx] = sqrtf(Kh + sq);
            kt[oidx] = sqrtf(Kh + sk);
        }
    }
    if (threadIdx.x < 16) Obf[(size_t)row * 1056 + 1040 + threadIdx.x] = (__bf16)0.f;
}

// ---------------------------------------------------------------- V transpose -> Vtb bf16 [bh][d][t] + vt norms
__global__ __launch_bounds__(256) void vtrans_k(
    const float* __restrict__ QKV, const float* __restrict__ curv,
    __bf16* __restrict__ Vtb, float* __restrict__ vt)
{
    __shared__ float sT[64 * 65];
    int bh = blockIdx.y; int h = bh & (HH - 1); int b = bh >> 4;
    int t0 = blockIdx.x * 64;
    int tid = threadIdx.x, w = tid >> 6, lane = tid & 63;
    float Kh = expf(curv[h]);
    const float* vbase = QKV + (size_t)(b * TT + t0) * 3072 + 2048 + h * 64;
#pragma unroll 4
    for (int i = 0; i < 16; i++) {
        int tr = w * 16 + i;
        float v = vbase[(size_t)tr * 3072 + lane];
        sT[lane * 65 + tr] = v;
        float s = v * v;
#pragma unroll
        for (int o = 32; o; o >>= 1) s += __shfl_xor(s, o);
        if (lane == 0) vt[(size_t)bh * TT + t0 + tr] = sqrtf(Kh + s);
    }
    __syncthreads();
    int d = tid >> 2, seg = tid & 3;
    const float* r = &sT[d * 65 + seg * 16];
    bf16x8 o0, o1;
#pragma unroll
    for (int i = 0; i < 8; i++) { o0[i] = (__bf16)r[i]; o1[i] = (__bf16)r[8 + i]; }
    __bf16* dst = Vtb + ((size_t)bh * 64 + d) * TT + t0 + seg * 16;
    *(bf16x8*)dst = o0;
    *(bf16x8*)(dst + 8) = o1;
}

// ---------------------------------------------------------------- MFMA flash hyperbolic attention (v6)
__global__ __launch_bounds__(256, 4) void flash_k(
    const float* __restrict__ QKV,
    const __bf16* __restrict__ Kb, const __bf16* __restrict__ Vtb,
    const float* __restrict__ qt, const float* __restrict__ kt,
    const float* __restrict__ vt,
    const float* __restrict__ curv,
    __bf16* __restrict__ O)
{
    __shared__ __bf16 sK[4096];     // [ksp][quad][s=64][8 d]
    __shared__ __bf16 sVt[4096];    // [ksp][quad][d=64][8 s]
    __shared__ __bf16 sP[4 * 16 * 72];
    __shared__ float skt[64], svt[64];

    int bh = blockIdx.x; int h = bh & (HH - 1); int b = bh >> 4;
    int pi = blockIdx.y;                   // pair index 0..31
    float Kh = expf(curv[h]);
    float sqKh = sqrtf(Kh), msqK = -sqKh, invKh = 1.0f / Kh;
    const float* tok = QKV + (size_t)b * TT * 3072 + h * 64;  // roped q fp32
    const char* KbB = (const char*)Kb + (size_t)bh * TT * 128;
    const char* VtB = (const char*)Vtb + (size_t)bh * 64 * (TT * 2);
    const float* qtp = qt + (size_t)bh * TT;
    const float* ktp = kt + (size_t)bh * TT;
    const float* vtp = vt + (size_t)bh * TT;

    int tid = threadIdx.x;
    int w = tid >> 6, lane = tid & 63;
    int m = lane & 15, quad = lane >> 4;
    int qA = pi * 32, qB = (63 - pi) * 32;
    int myBase = (w < 2) ? (qA + 16 * w) : (qB + 16 * (w - 2));
    int myJmax = (myBase + 15) >> 6;
    int blockJmax = (qB + 31) >> 6;
    __bf16* sPw = &sP[w * 16 * 72];

    // Q fragments (hi + lo bf16), A-layout: A[m][k=quad*8+j+32*ks]
    bf16x8 qhi[2], qlo[2];
    {
        const float* qrow = tok + (size_t)(myBase + m) * 3072;
#pragma unroll
        for (int ks = 0; ks < 2; ks++) {
            const float* s = qrow + quad * 8 + 32 * ks;
            float4 f0 = *(const float4*)s;
            float4 f1 = *(const float4*)(s + 4);
            float fa[8] = {f0.x, f0.y, f0.z, f0.w, f1.x, f1.y, f1.z, f1.w};
#pragma unroll
            for (int jj = 0; jj < 8; jj++) {
                __bf16 hv = (__bf16)fa[jj];
                qhi[ks][jj] = hv;
                qlo[ks][jj] = (__bf16)(fa[jj] - (float)hv);
            }
        }
    }
    float qtv[4]; int qg[4];
#pragma unroll
    for (int r = 0; r < 4; r++) { qg[r] = myBase + quad * 4 + r; qtv[r] = qtp[qg[r]]; }

    f32x4 zero = {0.f, 0.f, 0.f, 0.f};
    f32x4 accO[4];
#pragma unroll
    for (int nt = 0; nt < 4; nt++) accO[nt] = zero;
    float lsumr[4] = {}, o0r[4] = {};

    char* sKb  = (char*)sK  + w * 1024;
    char* sVb  = (char*)sVt + w * 1024;

    for (int j = 0; j <= blockJmax; ++j) {
        int sb = j << 6;
        __syncthreads();
        // ---- stage K/V tiles: 4 pure g2l16 per thread ----
        {
            const char* kg = KbB + (size_t)(sb + lane) * 128 + w * 16;
            g2l16(kg,      sKb);
            g2l16(kg + 64, sKb + 4096);
            const char* vg = VtB + (size_t)lane * (TT * 2) + sb * 2 + w * 16;
            g2l16(vg,      sVb);
            g2l16(vg + 64, sVb + 4096);
        }
        if (tid < 64) skt[tid] = ktp[sb + tid];
        else if (tid < 128) svt[tid - 64] = vtp[sb + tid - 64];
        __syncthreads();

        if (j > myJmax) continue;

        // ---- QK^T: S[16 x 64] ----
        f32x4 accS[4];
#pragma unroll
        for (int nt = 0; nt < 4; nt++) accS[nt] = zero;
#pragma unroll
        for (int nt = 0; nt < 4; nt++) {
#pragma unroll
            for (int ksp = 0; ksp < 2; ksp++) {
                bf16x8 bk = *(const bf16x8*)&sK[((ksp * 4 + quad) * 64 + nt * 16 + m) * 8];
                accS[nt] = __builtin_amdgcn_mfma_f32_16x16x32_bf16(qhi[ksp], bk, accS[nt], 0, 0, 0);
                accS[nt] = __builtin_amdgcn_mfma_f32_16x16x32_bf16(qlo[ksp], bk, accS[nt], 0, 0, 0);
            }
        }
        // ---- score epilogue: hyperbolic logit -> p, raw transcendentals ----
#pragma unroll
        for (int nt = 0; nt < 4; nt++) {
            int col = nt * 16 + m;
            int sglob = sb + col;
            float ktv = skt[col], vtv = svt[col];
#pragma unroll
            for (int r = 0; r < 4; r++) {
                float dot = accS[nt][r];
                float rdiff = fmaf(qtv[r], ktv, -dot);          // qt*kt - q.k
                float ratio = fmaxf(rdiff * invKh, 1.0f + 1e-7f);
                float y = ratio + fsqrt_(fmaf(ratio, ratio, -1.0f));
                float pv = fexp2(msqK * flog2(y));              // exp(-sqrt(K)*acosh)
                float p = (sglob <= qg[r]) ? pv : 0.0f;
                lsumr[r] += p;
                o0r[r] = fmaf(p, vtv, o0r[r]);
                sPw[(quad * 4 + r) * 72 + col] = (__bf16)p;
            }
        }
        __asm__ volatile("s_waitcnt lgkmcnt(0)" ::: "memory");
        // ---- PV: O += P @ V ----
#pragma unroll
        for (int ksp = 0; ksp < 2; ksp++) {
            bf16x8 aP = *(const bf16x8*)&sPw[m * 72 + ksp * 32 + quad * 8];
#pragma unroll
            for (int nt = 0; nt < 4; nt++) {
                bf16x8 bV = *(const bf16x8*)&sVt[((ksp * 4 + quad) * 64 + nt * 16 + m) * 8];
                accO[nt] = __builtin_amdgcn_mfma_f32_16x16x32_bf16(aP, bV, accO[nt], 0, 0, 0);
            }
        }
    }

    // ---- final: reduce lsum/o0 over the 16 col-lanes, normalize, write ----
#pragma unroll
    for (int r = 0; r < 4; r++) {
#pragma unroll
        for (int off = 1; off < 16; off <<= 1) {
            lsumr[r] += __shfl_xor(lsumr[r], off);
            o0r[r]   += __shfl_xor(o0r[r], off);
        }
    }
#pragma unroll
    for (int r = 0; r < 4; r++) {
        float inv = frcp_(lsumr[r]);
        float o0f = o0r[r] * inv;
        float ov[4]; float part = 0.f;
#pragma unroll
        for (int nt = 0; nt < 4; nt++) { float t = accO[nt][r] * inv; ov[nt] = t; part += t * t; }
        part += __shfl_xor(part, 1);
        part += __shfl_xor(part, 2);
        part += __shfl_xor(part, 4);
        part += __shfl_xor(part, 8);
        float scale = sqKh * frsq_(fmaxf(o0f * o0f - part, 1e-12f));
        size_t orow = (size_t)(b * TT + qg[r]) * 1056 + h * 65;
        if (m == 0) O[orow] = (__bf16)(o0f * scale);
#pragma unroll
        for (int nt = 0; nt < 4; nt++) O[orow + 1 + nt * 16 + m] = (__bf16)(ov[nt] * scale);
    }
}

// ---------------------------------------------------------------- launch
extern "C" void kernel_launch(void* const* d_in, const int* in_sizes, int n_in,
                              void* d_out, int out_size, void* d_ws, size_t ws_size,
                              hipStream_t stream) {
    const float* x    = (const float*)d_in[0];
    const float* bc   = (const float*)d_in[1];
    const float* mc   = (const float*)d_in[2];
    const float* ac   = (const float*)d_in[3];
    const float* w_qkv = (const float*)d_in[4];
    const float* w_ap  = (const float*)d_in[5];
    const float* b_ap  = (const float*)d_in[6];
    const float* w_me  = (const float*)d_in[7];
    const float* b_me  = (const float*)d_in[8];
    const float* w_ms  = (const float*)d_in[9];
    const float* b_ms  = (const float*)d_in[10];
    const float* lnw  = (const float*)d_in[11];
    const float* lnb  = (const float*)d_in[12];
    float* out = (float*)d_out;
    float* ws  = (float*)d_ws;

    // workspace (floats), total ~96.2 MB.
    // K padded 1056->1088 for the 256^2 GEMMs; h stride 4128->4224.
    float* R      = ws;
    float* qkvbuf = R;                             // M*3072 fp32 (dead after flash)
    float* X2     = R;                             // M*1024 fp32 (written step 5)
    __bf16* h_bf  = (__bf16*)(R + 4194304);        // M*4224 bf16 -> ends 12,845,056
    float* p      = R + 12845056;
    __bf16* ln_bf = (__bf16*)p;  p += 2228224;     // M*1088 bf16
    __bf16* o_bf  = (__bf16*)p;  p += 2162688;     // M*1056 bf16
    __bf16* qkvT  = (__bf16*)p;  p += 1671168;     // 3072*1088 bf16
    __bf16* apT   = (__bf16*)p;  p += 540672;      // 1024*1056 bf16
    float*  meT_f = p;           p += 2229856;     // 4099*1088 bf16 (after flash)
    float*  msT_f = p;           p += 2162688;     // 1024*4224 bf16 (after flash)
    float* Qt = p;               p += 2 * HH * TT;
    float* Kt = p;               p += 2 * HH * TT;
    float* Vt = p;
    __bf16* meT = (__bf16*)meT_f;
    __bf16* msT = (__bf16*)msT_f;
    __bf16* Kb  = (__bf16*)meT_f;   // 32*2048*64 bf16 <= meT slot; dead before wt_k(meT)
    __bf16* Vtb = (__bf16*)msT_f;   // same size      <= msT slot; dead before wt_k(msT)

    // 0. weight transposes needed before flash (Kp=1088, zero-filled past K)
    wt_k<<<dim3(34, 96),  256, 0, stream>>>(w_qkv, 1025, 3072, qkvT, 1088);
    wt_k<<<dim3(33, 32),  256, 0, stream>>>(w_ap,  1040, 1024, apT,  1056);

    // 1. ln1 = block_norm(project(x)) -> bf16 (stride 1088, zero pad)
    block_norm_bf_k<<<MM, 256, 0, stream>>>(x, 1024, ln_bf, 1088, lnw, lnb, bc);
    // 2. qkv = ln1 @ w_qkv -> fp32 (M,3072)   [256^2 8-phase, 192 blocks]
    mgemm256_k<false, false, false><<<dim3(12, 16), 512, 0, stream>>>(
        ln_bf, 1088, qkvT, 1088, 3072, nullptr, qkvbuf, 3072, 3072, 1088);
    // 3a. RoPE (q in place fp32, Kb bf16) + q/k norms + o_bf pad
    rope_k<<<MM, 256, 0, stream>>>(qkvbuf, ac, Qt, Kt, Kb, o_bf);
    // 3b. V transpose -> Vtb bf16 + v norms
    vtrans_k<<<dim3(32, 32), 256, 0, stream>>>(qkvbuf, ac, Vtb, Vt);
    // 4. MFMA flash attention -> o_t bf16 (M,1056)
    flash_k<<<dim3(2 * HH, 32), 256, 0, stream>>>(qkvbuf, Kb, Vtb, Qt, Kt, Vt, ac, o_bf);
    // 0b. remaining weight transposes (into the slots Kb/Vtb just vacated)
    wt_k<<<dim3(34, 129), 256, 0, stream>>>(w_me,  1025, 4099, meT, 1088);
    wt_k<<<dim3(132, 32), 256, 0, stream>>>(w_ms,  4100, 1024, msT, 4224);
    // 5. lx2[...,1:] = x + o_t @ w_attn_proj + b -> X2 fp32
    mgemm64_k<true, false, true><<<dim3(16, 32), 256, 0, stream>>>(
        o_bf, 1056, apT, 1056, b_ap, x, 1024, X2, 1024, 1024, 1056);
    // 6. ln2 = block_norm(lx2) -> bf16
    block_norm_bf_k<<<MM, 256, 0, stream>>>(X2, 1024, ln_bf, 1088, lnw, lnb, bc);
    // 7. h[1..4096] = gelu(ln2 @ w_mlp_expand + b) -> bf16   [256^2 8-phase, EXACT 16x16 grid]
    mgemm256_k<true, true, true><<<dim3(16, 16), 512, 0, stream>>>(
        ln_bf, 1088, meT, 1088, 4099, b_me, (void*)(h_bf + 1), 4224, 4099, 1088);
    // 8. h cols 4097..4099 (ragged tail vs meT rows 4096..4098) + x0 + pad
    row_x0_tail_k<<<MM, 256, 0, stream>>>(h_bf, ln_bf, meT, b_me, mc);
    // 9. out[...,1:] = lx2[...,1:] + h @ w_mlp_shrink + b
    mgemm64_k<true, false, true><<<dim3(16, 32), 256, 0, stream>>>(
        h_bf, 4224, msT, 4224, b_ms, X2, 1024, out + 1, 1025, 1024, 4224);
    // 10. out[...,0]
    row_x0_k<<<MM, 256, 0, stream>>>(out, 1025, 1024, bc);
}

// Round 3
// 478.196 us; speedup vs baseline: 1.1120x; 1.0691x over previous
//
#include <hip/hip_runtime.h>
#include <math.h>

// Problem constants: B=2, T=2048, E=1024, H=16, D=64; M = B*T = 4096
#define MM   4096
#define TT   2048
#define HH   16

typedef __bf16 bf16x8 __attribute__((ext_vector_type(8)));
typedef float f32x4 __attribute__((ext_vector_type(4)));

// async global->LDS, 16B per lane; LDS dest = wave-uniform base + lane*16
__device__ __forceinline__ void g2l16(const void* g, void* l) {
    __builtin_amdgcn_global_load_lds(
        (__attribute__((address_space(1))) void*)g,
        (__attribute__((address_space(3))) void*)l, 16, 0, 0);
}

// ---- raw transcendentals (guarded; libm fallback). Without -ffast-math the
// libm versions lower to multi-instruction OCML guard sequences — 3-4x cost.
#if __has_builtin(__builtin_amdgcn_exp2f)
__device__ __forceinline__ float fexp2(float x) { return __builtin_amdgcn_exp2f(x); }
#else
__device__ __forceinline__ float fexp2(float x) { return exp2f(x); }
#endif
#if __has_builtin(__builtin_amdgcn_logf)
__device__ __forceinline__ float flog2(float x) { return __builtin_amdgcn_logf(x); }
#else
__device__ __forceinline__ float flog2(float x) { return log2f(x); }
#endif
#if __has_builtin(__builtin_amdgcn_sqrtf)
__device__ __forceinline__ float fsqrt_(float x) { return __builtin_amdgcn_sqrtf(x); }
#else
__device__ __forceinline__ float fsqrt_(float x) { return sqrtf(x); }
#endif
#if __has_builtin(__builtin_amdgcn_rcpf)
__device__ __forceinline__ float frcp_(float x) { return __builtin_amdgcn_rcpf(x); }
#else
__device__ __forceinline__ float frcp_(float x) { return 1.0f / x; }
#endif
#if __has_builtin(__builtin_amdgcn_rsqf)
__device__ __forceinline__ float frsq_(float x) { return __builtin_amdgcn_rsqf(x); }
#else
__device__ __forceinline__ float frsq_(float x) { return rsqrtf(x); }
#endif

// ---------------------------------------------------------------- reductions
__device__ __forceinline__ float blockSum256(float v, volatile float* sb) {
    int lane = threadIdx.x & 63, w = threadIdx.x >> 6;
#pragma unroll
    for (int o = 32; o; o >>= 1) v += __shfl_xor(v, o);
    if (lane == 0) sb[w] = v;
    __syncthreads();
    v = sb[0] + sb[1] + sb[2] + sb[3];
    __syncthreads();
    return v;
}

// ---------------------------------------------------------------- block_norm -> bf16 (ldo-wide, zero pad)
__global__ __launch_bounds__(256) void block_norm_bf_k(
    const float* __restrict__ in, int ld,
    __bf16* __restrict__ out, int ldo,
    const float* __restrict__ lw, const float* __restrict__ lb,
    const float* __restrict__ curv)
{
    int row = blockIdx.x;
    const float* x = in + (size_t)row * ld;
    __bf16* o = out + (size_t)row * ldo;
    __shared__ float sb[4];
    int tid = threadIdx.x;
    float v[4]; float s1 = 0.f, s2 = 0.f;
#pragma unroll
    for (int r = 0; r < 4; r++) {
        float t = x[tid + 256 * r];
        v[r] = t; s1 += t; s2 += t * t;
    }
    s1 = blockSum256(s1, sb);
    s2 = blockSum256(s2, sb);
    float mean = s1 * (1.f / 1024.f);
    float var  = s2 * (1.f / 1024.f) - mean * mean;
    float rs = rsqrtf(var + 1e-5f);
    float y[4]; float ssq = 0.f;
#pragma unroll
    for (int r = 0; r < 4; r++) {
        int i = tid + 256 * r;
        float t = (v[r] - mean) * rs * lw[i] + lb[i];
        y[r] = t; ssq += t * t;
    }
    ssq = blockSum256(ssq, sb);
#pragma unroll
    for (int r = 0; r < 4; r++) o[1 + tid + 256 * r] = (__bf16)y[r];
    if (tid == 0) o[0] = (__bf16)sqrtf(expf(*curv) + ssq);
    if (tid < ldo - 1025) o[1025 + tid] = (__bf16)0.f;   // zero pad cols 1025..ldo-1
}

// ---------------------------------------------------------------- row x0 (fp32, final output)
__global__ __launch_bounds__(256) void row_x0_k(
    float* __restrict__ buf, int stride, int n, const float* __restrict__ curv)
{
    int row = blockIdx.x;
    float* base = buf + (size_t)row * stride;
    __shared__ float sb[4];
    float s = 0.f;
    for (int i = threadIdx.x; i < n; i += 256) { float t = base[1 + i]; s += t * t; }
    s = blockSum256(s, sb);
    if (threadIdx.x == 0) base[0] = sqrtf(expf(*curv) + s);
}

// ---------------------------------------------------------------- h tail (3 ragged cols) + x0 + pad (stride 4224)
__global__ __launch_bounds__(256) void row_x0_tail_k(
    __bf16* __restrict__ h,
    const __bf16* __restrict__ ln,      // ln2, stride 1088 (zero-padded past 1025)
    const __bf16* __restrict__ Bt,      // meT, stride 1088
    const float* __restrict__ bias,     // b_me (4099)
    const float* __restrict__ curv)
{
    int row = blockIdx.x;
    __bf16* base = h + (size_t)row * 4224;
    const __bf16* lnr = ln + (size_t)row * 1088;
    const __bf16* B0 = Bt + (size_t)4096 * 1088;
    const __bf16* B1 = Bt + (size_t)4097 * 1088;
    const __bf16* B2 = Bt + (size_t)4098 * 1088;
    __shared__ float sb[4];
    float d0 = 0.f, d1 = 0.f, d2 = 0.f;
    for (int i = threadIdx.x; i < 1088; i += 256) {
        float a = (float)lnr[i];
        d0 += a * (float)B0[i];
        d1 += a * (float)B1[i];
        d2 += a * (float)B2[i];
    }
    d0 = blockSum256(d0, sb);
    d1 = blockSum256(d1, sb);
    d2 = blockSum256(d2, sb);
    float t3[3] = {d0 + bias[4096], d1 + bias[4097], d2 + bias[4098]};
    float ssq_t = 0.f;
#pragma unroll
    for (int j = 0; j < 3; j++) {
        float v = t3[j];
        v = 0.5f * v * (1.f + erff(v * 0.70710678118654752f));
        t3[j] = v; ssq_t += v * v;
    }
    if (threadIdx.x == 0) {
        base[1 + 4096] = (__bf16)t3[0];
        base[1 + 4097] = (__bf16)t3[1];
        base[1 + 4098] = (__bf16)t3[2];
    }
    float s = 0.f;
    for (int i = threadIdx.x; i < 4096; i += 256) { float t = (float)base[1 + i]; s += t * t; }
    s = blockSum256(s, sb) + ssq_t;
    if (threadIdx.x == 0) base[0] = (__bf16)sqrtf(expf(*curv) + s);
    if (threadIdx.x < 124) base[4100 + threadIdx.x] = (__bf16)0.f;  // zero pad 4100..4223
}

// ---------------------------------------------------------------- weight convert + transpose
__global__ __launch_bounds__(256) void wt_k(
    const float* __restrict__ W, int K, int N,
    __bf16* __restrict__ Wt, int Kp)
{
    __shared__ float s[32][33];
    int tx = threadIdx.x & 31, ty = threadIdx.x >> 5;    // 32 x 8
    int k0 = blockIdx.x * 32, n0 = blockIdx.y * 32;
#pragma unroll
    for (int r = 0; r < 4; r++) {
        int k = k0 + ty + 8 * r, n = n0 + tx;
        s[ty + 8 * r][tx] = (k < K && n < N) ? W[(size_t)k * N + n] : 0.f;
    }
    __syncthreads();
#pragma unroll
    for (int r = 0; r < 4; r++) {
        int n = n0 + ty + 8 * r, k = k0 + tx;
        if (n < N) Wt[(size_t)n * Kp + k] = (__bf16)s[tx][ty + 8 * r];
    }
}

// ---------------------------------------------------------------- bf16 MFMA GEMM 256x256, BK=64, 8-phase
template<bool BIAS, bool GELU, bool OUTBF>
__global__ __launch_bounds__(512, 2) void mgemm256_k(
    const __bf16* __restrict__ A, int lda,
    const __bf16* __restrict__ Bt, int ldb, int NB,   // NB = valid rows of Bt (row clamp)
    const float* __restrict__ bias,
    void* __restrict__ Cout, int ldc,
    int N, int Kp)                                     // Kp multiple of 64
{
    __shared__ __bf16 sAB[65536];   // [A db0 |A db1 |B db0 |B db1] x 16384 elems
    const int tid = threadIdx.x;
    const int w = tid >> 6, lane = tid & 63;
    const int wm = w >> 2, wn = w & 3;
    const int lr = lane & 15, lq = lane >> 4;
    const int m0 = blockIdx.y * 256, n0 = blockIdx.x * 256;

    const int rr  = tid >> 3;
    const int csw = ((tid & 7) ^ (rr & 7)) << 3;   // elems
    const __bf16* gA[4]; const __bf16* gB[4];
#pragma unroll
    for (int c = 0; c < 4; c++) {
        gA[c] = A + (size_t)(m0 + c * 64 + rr) * lda + csw;
        int rb = n0 + c * 64 + rr; rb = (rb < NB) ? rb : (NB - 1);
        gB[c] = Bt + (size_t)rb * ldb + csw;
    }
    __bf16* lA = sAB + (w << 9);            // + db*16384 + c*4096
    __bf16* lB = sAB + 32768 + (w << 9);

    const int off0 = (lq * 8) ^ ((lr & 7) << 3);
    const int off1 = off0 ^ 32;
    const int arow = wm * 128 + lr;
    const int brow = wn * 64 + lr;

    f32x4 zero = {0.f, 0.f, 0.f, 0.f};
    f32x4 acc[8][4];
#pragma unroll
    for (int i = 0; i < 8; i++)
#pragma unroll
        for (int j = 0; j < 4; j++) acc[i][j] = zero;

    // prologue: stage K-tile 0 -> db0
#pragma unroll
    for (int c = 0; c < 4; c++) {
        g2l16(gA[c], lA + c * 4096);
        g2l16(gB[c], lB + c * 4096);
    }
    asm volatile("s_waitcnt vmcnt(0)" ::: "memory");
    __builtin_amdgcn_s_barrier();

    const int NT = Kp >> 6;
    for (int kt = 0; kt < NT; ++kt) {
        const int cur = kt & 1;
        const __bf16* pA = sAB + cur * 16384;
        const __bf16* pB = sAB + 32768 + cur * 16384;
        bf16x8 af[4][2], bfr[4][2];

        // ---- phase 1: issue next-tile stage early; read A half0 + B[0..1]; MFMA q00
        if (kt + 1 < NT) {
            const int ko = (kt + 1) << 6;
            __bf16* dA = lA + (cur ^ 1) * 16384;
            __bf16* dB = lB + (cur ^ 1) * 16384;
#pragma unroll
            for (int c = 0; c < 4; c++) {
                g2l16(gA[c] + ko, dA + c * 4096);
                g2l16(gB[c] + ko, dB + c * 4096);
            }
        }
#pragma unroll
        for (int i = 0; i < 4; i++) {
            const __bf16* r = pA + (arow + i * 16) * 64;
            af[i][0] = *(const bf16x8*)(r + off0);
            af[i][1] = *(const bf16x8*)(r + off1);
        }
#pragma unroll
        for (int j = 0; j < 2; j++) {
            const __bf16* r = pB + (brow + j * 16) * 64;
            bfr[j][0] = *(const bf16x8*)(r + off0);
            bfr[j][1] = *(const bf16x8*)(r + off1);
        }
        __builtin_amdgcn_s_barrier();
        __builtin_amdgcn_s_setprio(1);
#pragma unroll
        for (int ks = 0; ks < 2; ks++)
#pragma unroll
            for (int i = 0; i < 4; i++)
#pragma unroll
                for (int j = 0; j < 2; j++)
                    acc[i][j] = __builtin_amdgcn_mfma_f32_16x16x32_bf16(af[i][ks], bfr[j][ks], acc[i][j], 0, 0, 0);
        __builtin_amdgcn_s_setprio(0);
        __builtin_amdgcn_s_barrier();

        // ---- phase 2: read B[2..3]; MFMA q01
#pragma unroll
        for (int j = 2; j < 4; j++) {
            const __bf16* r = pB + (brow + j * 16) * 64;
            bfr[j][0] = *(const bf16x8*)(r + off0);
            bfr[j][1] = *(const bf16x8*)(r + off1);
        }
        __builtin_amdgcn_s_barrier();
        __builtin_amdgcn_s_setprio(1);
#pragma unroll
        for (int ks = 0; ks < 2; ks++)
#pragma unroll
            for (int i = 0; i < 4; i++)
#pragma unroll
                for (int j = 2; j < 4; j++)
                    acc[i][j] = __builtin_amdgcn_mfma_f32_16x16x32_bf16(af[i][ks], bfr[j][ks], acc[i][j], 0, 0, 0);
        __builtin_amdgcn_s_setprio(0);
        __builtin_amdgcn_s_barrier();

        // ---- phase 3: read A half1 (reuse af regs); MFMA q10
#pragma unroll
        for (int i = 0; i < 4; i++) {
            const __bf16* r = pA + (arow + 64 + i * 16) * 64;
            af[i][0] = *(const bf16x8*)(r + off0);
            af[i][1] = *(const bf16x8*)(r + off1);
        }
        __builtin_amdgcn_s_barrier();
        __builtin_amdgcn_s_setprio(1);
#pragma unroll
        for (int ks = 0; ks < 2; ks++)
#pragma unroll
            for (int i = 0; i < 4; i++)
#pragma unroll
                for (int j = 0; j < 2; j++)
                    acc[4 + i][j] = __builtin_amdgcn_mfma_f32_16x16x32_bf16(af[i][ks], bfr[j][ks], acc[4 + i][j], 0, 0, 0);
        __builtin_amdgcn_s_setprio(0);
        __builtin_amdgcn_s_barrier();

        // ---- phase 4: MFMA q11; tile boundary (the ONLY vmcnt wait per tile)
        __builtin_amdgcn_s_setprio(1);
#pragma unroll
        for (int ks = 0; ks < 2; ks++)
#pragma unroll
            for (int i = 0; i < 4; i++)
#pragma unroll
                for (int j = 2; j < 4; j++)
                    acc[4 + i][j] = __builtin_amdgcn_mfma_f32_16x16x32_bf16(af[i][ks], bfr[j][ks], acc[4 + i][j], 0, 0, 0);
        __builtin_amdgcn_s_setprio(0);
        asm volatile("s_waitcnt vmcnt(0) lgkmcnt(0)" ::: "memory");
        __builtin_amdgcn_s_barrier();
    }

    // ---- epilogue
#pragma unroll
    for (int j = 0; j < 4; j++) {
        const int n = n0 + wn * 64 + j * 16 + lr;
        if (n < N) {
            const float bv = BIAS ? bias[n] : 0.f;
#pragma unroll
            for (int i = 0; i < 8; i++) {
#pragma unroll
                for (int r = 0; r < 4; r++) {
                    const int m = m0 + wm * 128 + i * 16 + lq * 4 + r;
                    float v = acc[i][j][r] + bv;
                    if (GELU) v = 0.5f * v * (1.f + erff(v * 0.70710678118654752f));
                    if (OUTBF) ((__bf16*)Cout)[(size_t)m * ldc + n] = (__bf16)v;
                    else       ((float*)Cout)[(size_t)m * ldc + n] = v;
                }
            }
        }
    }
}

// ---------------------------------------------------------------- bf16 MFMA GEMM 128x128, BK=64, pipelined
// For M=4096, N=1024 (attn-proj K=1088, shrink K=4224). 256 thr (4 waves,
// 2M x 2N), per-wave C = 64x64 (acc[4][4]). LDS 64 KiB double-buffered ->
// 2 blocks/CU (cross-block overlap covers the tile-boundary drain).
// Same XOR-swizzle + phase discipline as mgemm256_k, 2 phases of 16 MFMA
// per K-tile, next-tile g2l16 issued at phase 1, single vmcnt wait per tile.
// Grid: 1D 256 blocks, bijective XCD swizzle -> each XCD owns 4 A-panels.
template<bool BIAS, bool GELU, bool SKIP>
__global__ __launch_bounds__(256, 2) void mgemm128_k(
    const __bf16* __restrict__ A, int lda,
    const __bf16* __restrict__ Bt, int ldb,
    const float* __restrict__ bias,
    const float* __restrict__ skip, int ldskip,
    float* __restrict__ Cout, int ldc,
    int N, int Kp)                                     // Kp multiple of 64; N=1024, grid 256
{
    __shared__ __bf16 sAB[32768];   // [A db0 |A db1 |B db0 |B db1] x 8192 elems
    const int tid = threadIdx.x;
    const int w = tid >> 6, lane = tid & 63;
    const int wm = w >> 1, wn = w & 1;
    const int lr = lane & 15, lq = lane >> 4;

    // bijective XCD swizzle: XCD k gets swz in [k*cpx, (k+1)*cpx) -> 4 contiguous m-panels
    const int bid = blockIdx.x;
    const int cpx = gridDim.x >> 3;                 // 32
    const int swz = (bid & 7) * cpx + (bid >> 3);
    const int m0 = (swz >> 3) * 128, n0 = (swz & 7) * 128;

    // staging: 4 chunks of 32 rows x 64 K (4 KB each); thread covers row rr,
    // 16B slot (tid&7); source col pre-XOR-swizzled (rule-21 both-sides).
    const int rr  = tid >> 3;
    const int csw = ((tid & 7) ^ (rr & 7)) << 3;
    const __bf16* gA[4]; const __bf16* gB[4];
#pragma unroll
    for (int c = 0; c < 4; c++) {
        gA[c] = A + (size_t)(m0 + c * 32 + rr) * lda + csw;
        gB[c] = Bt + (size_t)(n0 + c * 32 + rr) * ldb + csw;
    }
    __bf16* lA = sAB + (w << 9);            // + db*8192 + c*2048
    __bf16* lB = sAB + 16384 + (w << 9);

    const int off0 = (lq * 8) ^ ((lr & 7) << 3);
    const int off1 = off0 ^ 32;
    const int arow = wm * 64 + lr;
    const int brow = wn * 64 + lr;

    f32x4 zero = {0.f, 0.f, 0.f, 0.f};
    f32x4 acc[4][4];
#pragma unroll
    for (int i = 0; i < 4; i++)
#pragma unroll
        for (int j = 0; j < 4; j++) acc[i][j] = zero;

    // prologue: stage K-tile 0 -> db0
#pragma unroll
    for (int c = 0; c < 4; c++) {
        g2l16(gA[c], lA + c * 2048);
        g2l16(gB[c], lB + c * 2048);
    }
    asm volatile("s_waitcnt vmcnt(0)" ::: "memory");
    __builtin_amdgcn_s_barrier();

    const int NT = Kp >> 6;
    for (int kt = 0; kt < NT; ++kt) {
        const int cur = kt & 1;
        const __bf16* pA = sAB + cur * 8192;
        const __bf16* pB = sAB + 16384 + cur * 8192;
        bf16x8 af[4][2], bfr[4][2];

        // ---- phase 1: issue next-tile stage; read all A + B[0..1]; 16 MFMA (j=0,1)
        if (kt + 1 < NT) {
            const int ko = (kt + 1) << 6;
            __bf16* dA = lA + (cur ^ 1) * 8192;
            __bf16* dB = lB + (cur ^ 1) * 8192;
#pragma unroll
            for (int c = 0; c < 4; c++) {
                g2l16(gA[c] + ko, dA + c * 2048);
                g2l16(gB[c] + ko, dB + c * 2048);
            }
        }
#pragma unroll
        for (int i = 0; i < 4; i++) {
            const __bf16* r = pA + (arow + i * 16) * 64;
            af[i][0] = *(const bf16x8*)(r + off0);
            af[i][1] = *(const bf16x8*)(r + off1);
        }
#pragma unroll
        for (int j = 0; j < 2; j++) {
            const __bf16* r = pB + (brow + j * 16) * 64;
            bfr[j][0] = *(const bf16x8*)(r + off0);
            bfr[j][1] = *(const bf16x8*)(r + off1);
        }
        __builtin_amdgcn_s_barrier();
        __builtin_amdgcn_s_setprio(1);
#pragma unroll
        for (int ks = 0; ks < 2; ks++)
#pragma unroll
            for (int i = 0; i < 4; i++)
#pragma unroll
                for (int j = 0; j < 2; j++)
                    acc[i][j] = __builtin_amdgcn_mfma_f32_16x16x32_bf16(af[i][ks], bfr[j][ks], acc[i][j], 0, 0, 0);
        __builtin_amdgcn_s_setprio(0);
        __builtin_amdgcn_s_barrier();

        // ---- phase 2: read B[2..3]; 16 MFMA (j=2,3); tile boundary
#pragma unroll
        for (int j = 2; j < 4; j++) {
            const __bf16* r = pB + (brow + j * 16) * 64;
            bfr[j][0] = *(const bf16x8*)(r + off0);
            bfr[j][1] = *(const bf16x8*)(r + off1);
        }
        __builtin_amdgcn_s_barrier();
        __builtin_amdgcn_s_setprio(1);
#pragma unroll
        for (int ks = 0; ks < 2; ks++)
#pragma unroll
            for (int i = 0; i < 4; i++)
#pragma unroll
                for (int j = 2; j < 4; j++)
                    acc[i][j] = __builtin_amdgcn_mfma_f32_16x16x32_bf16(af[i][ks], bfr[j][ks], acc[i][j], 0, 0, 0);
        __builtin_amdgcn_s_setprio(0);
        asm volatile("s_waitcnt vmcnt(0) lgkmcnt(0)" ::: "memory");
        __builtin_amdgcn_s_barrier();
    }

    // ---- epilogue
#pragma unroll
    for (int j = 0; j < 4; j++) {
        const int n = n0 + wn * 64 + j * 16 + lr;
        if (n < N) {
            const float bv = BIAS ? bias[n] : 0.f;
#pragma unroll
            for (int i = 0; i < 4; i++) {
#pragma unroll
                for (int r = 0; r < 4; r++) {
                    const int m = m0 + wm * 64 + i * 16 + lq * 4 + r;
                    float v = acc[i][j][r] + bv;
                    if (GELU) v = 0.5f * v * (1.f + erff(v * 0.70710678118654752f));
                    if (SKIP) v += skip[(size_t)m * ldskip + n];
                    Cout[(size_t)m * ldc + n] = v;
                }
            }
        }
    }
}

// ---------------------------------------------------------------- RoPE in-place(q) + Kb bf16 + q/k norms
__global__ __launch_bounds__(256) void rope_k(
    float* __restrict__ QKV, const float* __restrict__ curv,
    float* __restrict__ qt, float* __restrict__ kt,
    __bf16* __restrict__ Kb, __bf16* __restrict__ Obf)
{
    int row = blockIdx.x;              // b*T + t
    int b = row >> 11, t = row & (TT - 1);
    int wv = threadIdx.x >> 6, d = threadIdx.x & 63;
    int j = d & 31;
    float fr = (float)t * powf(10000.0f, -(float)(2 * j) / 64.0f);
    float cv = cosf(fr), sv = sinf(fr);
    float sgn = (d < 32) ? sv : -sv;
    for (int h = wv; h < HH; h += 4) {
        float Kh = expf(curv[h]);
        float* base = QKV + (size_t)row * 3072 + h * 64;
        float q = base[d], k = base[1024 + d];
        float qp = __shfl_xor(q, 32);
        float kp = __shfl_xor(k, 32);
        float qr = q * cv + qp * sgn;
        float kr = k * cv + kp * sgn;
        base[d] = qr;                         // q roped in place (fp32 for hi/lo split)
        size_t oidx = ((size_t)(b * HH + h) * TT + t);
        Kb[oidx * 64 + d] = (__bf16)kr;       // roped k, bf16 head-major
        float sq = qr * qr, sk = kr * kr;
#pragma unroll
        for (int o = 32; o; o >>= 1) {
            sq += __shfl_xor(sq, o);
            sk += __shfl_xor(sk, o);
        }
        if (d == 0) {
            qt[oidx] = sqrtf(Kh + sq);
            kt[oidx] = sqrtf(Kh + sk);
        }
    }
    if (threadIdx.x < 48) Obf[(size_t)row * 1088 + 1040 + threadIdx.x] = (__bf16)0.f;
}

// ---------------------------------------------------------------- V transpose -> Vtb bf16 [bh][d][t] + vt norms
__global__ __launch_bounds__(256) void vtrans_k(
    const float* __restrict__ QKV, const float* __restrict__ curv,
    __bf16* __restrict__ Vtb, float* __restrict__ vt)
{
    __shared__ float sT[64 * 65];
    int bh = blockIdx.y; int h = bh & (HH - 1); int b = bh >> 4;
    int t0 = blockIdx.x * 64;
    int tid = threadIdx.x, w = tid >> 6, lane = tid & 63;
    float Kh = expf(curv[h]);
    const float* vbase = QKV + (size_t)(b * TT + t0) * 3072 + 2048 + h * 64;
#pragma unroll 4
    for (int i = 0; i < 16; i++) {
        int tr = w * 16 + i;
        float v = vbase[(size_t)tr * 3072 + lane];
        sT[lane * 65 + tr] = v;
        float s = v * v;
#pragma unroll
        for (int o = 32; o; o >>= 1) s += __shfl_xor(s, o);
        if (lane == 0) vt[(size_t)bh * TT + t0 + tr] = sqrtf(Kh + s);
    }
    __syncthreads();
    int d = tid >> 2, seg = tid & 3;
    const float* r = &sT[d * 65 + seg * 16];
    bf16x8 o0, o1;
#pragma unroll
    for (int i = 0; i < 8; i++) { o0[i] = (__bf16)r[i]; o1[i] = (__bf16)r[8 + i]; }
    __bf16* dst = Vtb + ((size_t)bh * 64 + d) * TT + t0 + seg * 16;
    *(bf16x8*)dst = o0;
    *(bf16x8*)(dst + 8) = o1;
}

// ---------------------------------------------------------------- MFMA flash hyperbolic attention (v6)
__global__ __launch_bounds__(256, 4) void flash_k(
    const float* __restrict__ QKV,
    const __bf16* __restrict__ Kb, const __bf16* __restrict__ Vtb,
    const float* __restrict__ qt, const float* __restrict__ kt,
    const float* __restrict__ vt,
    const float* __restrict__ curv,
    __bf16* __restrict__ O)
{
    __shared__ __bf16 sK[4096];     // [ksp][quad][s=64][8 d]
    __shared__ __bf16 sVt[4096];    // [ksp][quad][d=64][8 s]
    __shared__ __bf16 sP[4 * 16 * 72];
    __shared__ float skt[64], svt[64];

    int bh = blockIdx.x; int h = bh & (HH - 1); int b = bh >> 4;
    int pi = blockIdx.y;                   // pair index 0..31
    float Kh = expf(curv[h]);
    float sqKh = sqrtf(Kh), msqK = -sqKh, invKh = 1.0f / Kh;
    const float* tok = QKV + (size_t)b * TT * 3072 + h * 64;  // roped q fp32
    const char* KbB = (const char*)Kb + (size_t)bh * TT * 128;
    const char* VtB = (const char*)Vtb + (size_t)bh * 64 * (TT * 2);
    const float* qtp = qt + (size_t)bh * TT;
    const float* ktp = kt + (size_t)bh * TT;
    const float* vtp = vt + (size_t)bh * TT;

    int tid = threadIdx.x;
    int w = tid >> 6, lane = tid & 63;
    int m = lane & 15, quad = lane >> 4;
    int qA = pi * 32, qB = (63 - pi) * 32;
    int myBase = (w < 2) ? (qA + 16 * w) : (qB + 16 * (w - 2));
    int myJmax = (myBase + 15) >> 6;
    int blockJmax = (qB + 31) >> 6;
    __bf16* sPw = &sP[w * 16 * 72];

    // Q fragments (hi + lo bf16), A-layout: A[m][k=quad*8+j+32*ks]
    bf16x8 qhi[2], qlo[2];
    {
        const float* qrow = tok + (size_t)(myBase + m) * 3072;
#pragma unroll
        for (int ks = 0; ks < 2; ks++) {
            const float* s = qrow + quad * 8 + 32 * ks;
            float4 f0 = *(const float4*)s;
            float4 f1 = *(const float4*)(s + 4);
            float fa[8] = {f0.x, f0.y, f0.z, f0.w, f1.x, f1.y, f1.z, f1.w};
#pragma unroll
            for (int jj = 0; jj < 8; jj++) {
                __bf16 hv = (__bf16)fa[jj];
                qhi[ks][jj] = hv;
                qlo[ks][jj] = (__bf16)(fa[jj] - (float)hv);
            }
        }
    }
    float qtv[4]; int qg[4];
#pragma unroll
    for (int r = 0; r < 4; r++) { qg[r] = myBase + quad * 4 + r; qtv[r] = qtp[qg[r]]; }

    f32x4 zero = {0.f, 0.f, 0.f, 0.f};
    f32x4 accO[4];
#pragma unroll
    for (int nt = 0; nt < 4; nt++) accO[nt] = zero;
    float lsumr[4] = {}, o0r[4] = {};

    char* sKb  = (char*)sK  + w * 1024;
    char* sVb  = (char*)sVt + w * 1024;

    for (int j = 0; j <= blockJmax; ++j) {
        int sb = j << 6;
        __syncthreads();
        // ---- stage K/V tiles: 4 pure g2l16 per thread ----
        {
            const char* kg = KbB + (size_t)(sb + lane) * 128 + w * 16;
            g2l16(kg,      sKb);
            g2l16(kg + 64, sKb + 4096);
            const char* vg = VtB + (size_t)lane * (TT * 2) + sb * 2 + w * 16;
            g2l16(vg,      sVb);
            g2l16(vg + 64, sVb + 4096);
        }
        if (tid < 64) skt[tid] = ktp[sb + tid];
        else if (tid < 128) svt[tid - 64] = vtp[sb + tid - 64];
        __syncthreads();

        if (j > myJmax) continue;

        // ---- QK^T: S[16 x 64] ----
        f32x4 accS[4];
#pragma unroll
        for (int nt = 0; nt < 4; nt++) accS[nt] = zero;
#pragma unroll
        for (int nt = 0; nt < 4; nt++) {
#pragma unroll
            for (int ksp = 0; ksp < 2; ksp++) {
                bf16x8 bk = *(const bf16x8*)&sK[((ksp * 4 + quad) * 64 + nt * 16 + m) * 8];
                accS[nt] = __builtin_amdgcn_mfma_f32_16x16x32_bf16(qhi[ksp], bk, accS[nt], 0, 0, 0);
                accS[nt] = __builtin_amdgcn_mfma_f32_16x16x32_bf16(qlo[ksp], bk, accS[nt], 0, 0, 0);
            }
        }
        // ---- score epilogue: hyperbolic logit -> p, raw transcendentals ----
#pragma unroll
        for (int nt = 0; nt < 4; nt++) {
            int col = nt * 16 + m;
            int sglob = sb + col;
            float ktv = skt[col], vtv = svt[col];
#pragma unroll
            for (int r = 0; r < 4; r++) {
                float dot = accS[nt][r];
                float rdiff = fmaf(qtv[r], ktv, -dot);          // qt*kt - q.k
                float ratio = fmaxf(rdiff * invKh, 1.0f + 1e-7f);
                float y = ratio + fsqrt_(fmaf(ratio, ratio, -1.0f));
                float pv = fexp2(msqK * flog2(y));              // exp(-sqrt(K)*acosh)
                float p = (sglob <= qg[r]) ? pv : 0.0f;
                lsumr[r] += p;
                o0r[r] = fmaf(p, vtv, o0r[r]);
                sPw[(quad * 4 + r) * 72 + col] = (__bf16)p;
            }
        }
        __asm__ volatile("s_waitcnt lgkmcnt(0)" ::: "memory");
        // ---- PV: O += P @ V ----
#pragma unroll
        for (int ksp = 0; ksp < 2; ksp++) {
            bf16x8 aP = *(const bf16x8*)&sPw[m * 72 + ksp * 32 + quad * 8];
#pragma unroll
            for (int nt = 0; nt < 4; nt++) {
                bf16x8 bV = *(const bf16x8*)&sVt[((ksp * 4 + quad) * 64 + nt * 16 + m) * 8];
                accO[nt] = __builtin_amdgcn_mfma_f32_16x16x32_bf16(aP, bV, accO[nt], 0, 0, 0);
            }
        }
    }

    // ---- final: reduce lsum/o0 over the 16 col-lanes, normalize, write ----
#pragma unroll
    for (int r = 0; r < 4; r++) {
#pragma unroll
        for (int off = 1; off < 16; off <<= 1) {
            lsumr[r] += __shfl_xor(lsumr[r], off);
            o0r[r]   += __shfl_xor(o0r[r], off);
        }
    }
#pragma unroll
    for (int r = 0; r < 4; r++) {
        float inv = frcp_(lsumr[r]);
        float o0f = o0r[r] * inv;
        float ov[4]; float part = 0.f;
#pragma unroll
        for (int nt = 0; nt < 4; nt++) { float t = accO[nt][r] * inv; ov[nt] = t; part += t * t; }
        part += __shfl_xor(part, 1);
        part += __shfl_xor(part, 2);
        part += __shfl_xor(part, 4);
        part += __shfl_xor(part, 8);
        float scale = sqKh * frsq_(fmaxf(o0f * o0f - part, 1e-12f));
        size_t orow = (size_t)(b * TT + qg[r]) * 1088 + h * 65;
        if (m == 0) O[orow] = (__bf16)(o0f * scale);
#pragma unroll
        for (int nt = 0; nt < 4; nt++) O[orow + 1 + nt * 16 + m] = (__bf16)(ov[nt] * scale);
    }
}

// ---------------------------------------------------------------- launch
extern "C" void kernel_launch(void* const* d_in, const int* in_sizes, int n_in,
                              void* d_out, int out_size, void* d_ws, size_t ws_size,
                              hipStream_t stream) {
    const float* x    = (const float*)d_in[0];
    const float* bc   = (const float*)d_in[1];
    const float* mc   = (const float*)d_in[2];
    const float* ac   = (const float*)d_in[3];
    const float* w_qkv = (const float*)d_in[4];
    const float* w_ap  = (const float*)d_in[5];
    const float* b_ap  = (const float*)d_in[6];
    const float* w_me  = (const float*)d_in[7];
    const float* b_me  = (const float*)d_in[8];
    const float* w_ms  = (const float*)d_in[9];
    const float* b_ms  = (const float*)d_in[10];
    const float* lnw  = (const float*)d_in[11];
    const float* lnb  = (const float*)d_in[12];
    float* out = (float*)d_out;
    float* ws  = (float*)d_ws;

    // workspace (floats), total ~96.5 MB.
    // K padded 1056->1088 for all K-dim-1056 GEMMs; h stride 4224; o_bf stride 1088.
    float* R      = ws;
    float* qkvbuf = R;                             // M*3072 fp32 (dead after flash)
    float* X2     = R;                             // M*1024 fp32 (written step 5)
    __bf16* h_bf  = (__bf16*)(R + 4194304);        // M*4224 bf16 -> ends 12,845,056
    float* p      = R + 12845056;
    __bf16* ln_bf = (__bf16*)p;  p += 2228224;     // M*1088 bf16
    __bf16* o_bf  = (__bf16*)p;  p += 2228224;     // M*1088 bf16
    __bf16* qkvT  = (__bf16*)p;  p += 1671168;     // 3072*1088 bf16
    __bf16* apT   = (__bf16*)p;  p += 557056;      // 1024*1088 bf16
    float*  meT_f = p;           p += 2229856;     // 4099*1088 bf16 (after flash)
    float*  msT_f = p;           p += 2162688;     // 1024*4224 bf16 (after flash)
    float* Qt = p;               p += 2 * HH * TT;
    float* Kt = p;               p += 2 * HH * TT;
    float* Vt = p;
    __bf16* meT = (__bf16*)meT_f;
    __bf16* msT = (__bf16*)msT_f;
    __bf16* Kb  = (__bf16*)meT_f;   // 32*2048*64 bf16 <= meT slot; dead before wt_k(meT)
    __bf16* Vtb = (__bf16*)msT_f;   // same size      <= msT slot; dead before wt_k(msT)

    // 0. weight transposes needed before flash (zero-filled past K)
    wt_k<<<dim3(34, 96),  256, 0, stream>>>(w_qkv, 1025, 3072, qkvT, 1088);
    wt_k<<<dim3(34, 32),  256, 0, stream>>>(w_ap,  1040, 1024, apT,  1088);

    // 1. ln1 = block_norm(project(x)) -> bf16 (stride 1088, zero pad)
    block_norm_bf_k<<<MM, 256, 0, stream>>>(x, 1024, ln_bf, 1088, lnw, lnb, bc);
    // 2. qkv = ln1 @ w_qkv -> fp32 (M,3072)   [256^2 8-phase, 192 blocks]
    mgemm256_k<false, false, false><<<dim3(12, 16), 512, 0, stream>>>(
        ln_bf, 1088, qkvT, 1088, 3072, nullptr, qkvbuf, 3072, 3072, 1088);
    // 3a. RoPE (q in place fp32, Kb bf16) + q/k norms + o_bf pad (cols 1040..1087)
    rope_k<<<MM, 256, 0, stream>>>(qkvbuf, ac, Qt, Kt, Kb, o_bf);
    // 3b. V transpose -> Vtb bf16 + v norms
    vtrans_k<<<dim3(32, 32), 256, 0, stream>>>(qkvbuf, ac, Vtb, Vt);
    // 4. MFMA flash attention -> o_t bf16 (M,1088)
    flash_k<<<dim3(2 * HH, 32), 256, 0, stream>>>(qkvbuf, Kb, Vtb, Qt, Kt, Vt, ac, o_bf);
    // 0b. remaining weight transposes (into the slots Kb/Vtb just vacated)
    wt_k<<<dim3(34, 129), 256, 0, stream>>>(w_me,  1025, 4099, meT, 1088);
    wt_k<<<dim3(132, 32), 256, 0, stream>>>(w_ms,  4100, 1024, msT, 4224);
    // 5. lx2[...,1:] = x + o_t @ w_attn_proj + b -> X2 fp32   [128^2 pipelined]
    mgemm128_k<true, false, true><<<dim3(256), 256, 0, stream>>>(
        o_bf, 1088, apT, 1088, b_ap, x, 1024, X2, 1024, 1024, 1088);
    // 6. ln2 = block_norm(lx2) -> bf16
    block_norm_bf_k<<<MM, 256, 0, stream>>>(X2, 1024, ln_bf, 1088, lnw, lnb, bc);
    // 7. h[1..4096] = gelu(ln2 @ w_mlp_expand + b) -> bf16   [256^2 8-phase, EXACT 16x16 grid]
    mgemm256_k<true, true, true><<<dim3(16, 16), 512, 0, stream>>>(
        ln_bf, 1088, meT, 1088, 4099, b_me, (void*)(h_bf + 1), 4224, 4099, 1088);
    // 8. h cols 4097..4099 (ragged tail vs meT rows 4096..4098) + x0 + pad
    row_x0_tail_k<<<MM, 256, 0, stream>>>(h_bf, ln_bf, meT, b_me, mc);
    // 9. out[...,1:] = lx2[...,1:] + h @ w_mlp_shrink + b   [128^2 pipelined]
    mgemm128_k<true, false, true><<<dim3(256), 256, 0, stream>>>(
        h_bf, 4224, msT, 4224, b_ms, X2, 1024, out + 1, 1025, 1024, 4224);
    // 10. out[...,0]
    row_x0_k<<<MM, 256, 0, stream>>>(out, 1025, 1024, bc);
}

// Round 4
// 453.510 us; speedup vs baseline: 1.1725x; 1.0544x over previous
//
#include <hip/hip_runtime.h>
#include <math.h>

// Problem constants: B=2, T=2048, E=1024, H=16, D=64; M = B*T = 4096
#define MM   4096
#define TT   2048
#define HH   16

typedef __bf16 bf16x8 __attribute__((ext_vector_type(8)));
typedef float f32x4 __attribute__((ext_vector_type(4)));

// async global->LDS, 16B per lane; LDS dest = wave-uniform base + lane*16
__device__ __forceinline__ void g2l16(const void* g, void* l) {
    __builtin_amdgcn_global_load_lds(
        (__attribute__((address_space(1))) void*)g,
        (__attribute__((address_space(3))) void*)l, 16, 0, 0);
}

// ---- raw transcendentals (guarded; libm fallback). Without -ffast-math the
// libm versions lower to multi-instruction OCML guard sequences — 3-4x cost.
#if __has_builtin(__builtin_amdgcn_exp2f)
__device__ __forceinline__ float fexp2(float x) { return __builtin_amdgcn_exp2f(x); }
#else
__device__ __forceinline__ float fexp2(float x) { return exp2f(x); }
#endif
#if __has_builtin(__builtin_amdgcn_logf)
__device__ __forceinline__ float flog2(float x) { return __builtin_amdgcn_logf(x); }
#else
__device__ __forceinline__ float flog2(float x) { return log2f(x); }
#endif
#if __has_builtin(__builtin_amdgcn_sqrtf)
__device__ __forceinline__ float fsqrt_(float x) { return __builtin_amdgcn_sqrtf(x); }
#else
__device__ __forceinline__ float fsqrt_(float x) { return sqrtf(x); }
#endif
#if __has_builtin(__builtin_amdgcn_rcpf)
__device__ __forceinline__ float frcp_(float x) { return __builtin_amdgcn_rcpf(x); }
#else
__device__ __forceinline__ float frcp_(float x) { return 1.0f / x; }
#endif
#if __has_builtin(__builtin_amdgcn_rsqf)
__device__ __forceinline__ float frsq_(float x) { return __builtin_amdgcn_rsqf(x); }
#else
__device__ __forceinline__ float frsq_(float x) { return rsqrtf(x); }
#endif

// fast GELU (tanh form, abs err ~1e-3; ref tolerance 0.25 and downstream
// weights are 0.02-scale -> negligible). Replaces libm erff (~35 VALU ops).
__device__ __forceinline__ float gelu_f(float x) {
    float u = 0.7978845608028654f * fmaf(0.044715f * x, x * x, x);
    u = fminf(fmaxf(u, -15.f), 15.f);
    float t = fexp2(-2.885390081777927f * u);     // e^{-2u}
    return 0.5f * x * (1.f + (1.f - t) * frcp_(1.f + t));
}

// ---------------------------------------------------------------- reductions
__device__ __forceinline__ float blockSum256(float v, volatile float* sb) {
    int lane = threadIdx.x & 63, w = threadIdx.x >> 6;
#pragma unroll
    for (int o = 32; o; o >>= 1) v += __shfl_xor(v, o);
    if (lane == 0) sb[w] = v;
    __syncthreads();
    v = sb[0] + sb[1] + sb[2] + sb[3];
    __syncthreads();
    return v;
}

// ---------------------------------------------------------------- block_norm -> bf16 (ldo-wide, zero pad)
__global__ __launch_bounds__(256) void block_norm_bf_k(
    const float* __restrict__ in, int ld,
    __bf16* __restrict__ out, int ldo,
    const float* __restrict__ lw, const float* __restrict__ lb,
    const float* __restrict__ curv)
{
    int row = blockIdx.x;
    const float* x = in + (size_t)row * ld;
    __bf16* o = out + (size_t)row * ldo;
    __shared__ float sb[4];
    int tid = threadIdx.x;
    float v[4]; float s1 = 0.f, s2 = 0.f;
#pragma unroll
    for (int r = 0; r < 4; r++) {
        float t = x[tid + 256 * r];
        v[r] = t; s1 += t; s2 += t * t;
    }
    s1 = blockSum256(s1, sb);
    s2 = blockSum256(s2, sb);
    float mean = s1 * (1.f / 1024.f);
    float var  = s2 * (1.f / 1024.f) - mean * mean;
    float rs = rsqrtf(var + 1e-5f);
    float y[4]; float ssq = 0.f;
#pragma unroll
    for (int r = 0; r < 4; r++) {
        int i = tid + 256 * r;
        float t = (v[r] - mean) * rs * lw[i] + lb[i];
        y[r] = t; ssq += t * t;
    }
    ssq = blockSum256(ssq, sb);
#pragma unroll
    for (int r = 0; r < 4; r++) o[1 + tid + 256 * r] = (__bf16)y[r];
    if (tid == 0) o[0] = (__bf16)sqrtf(expf(*curv) + ssq);
    if (tid < ldo - 1025) o[1025 + tid] = (__bf16)0.f;   // zero pad cols 1025..ldo-1
}

// ---------------------------------------------------------------- row x0 (fp32, final output)
__global__ __launch_bounds__(256) void row_x0_k(
    float* __restrict__ buf, int stride, int n, const float* __restrict__ curv)
{
    int row = blockIdx.x;
    float* base = buf + (size_t)row * stride;
    __shared__ float sb[4];
    float s = 0.f;
    for (int i = threadIdx.x; i < n; i += 256) { float t = base[1 + i]; s += t * t; }
    s = blockSum256(s, sb);
    if (threadIdx.x == 0) base[0] = sqrtf(expf(*curv) + s);
}

// ---------------------------------------------------------------- h tail (3 ragged cols) + x0 + pad (stride 4224)
__global__ __launch_bounds__(256) void row_x0_tail_k(
    __bf16* __restrict__ h,
    const __bf16* __restrict__ ln,      // ln2, stride 1088 (zero-padded past 1025)
    const __bf16* __restrict__ Bt,      // meT, stride 1088
    const float* __restrict__ bias,     // b_me (4099)
    const float* __restrict__ curv)
{
    int row = blockIdx.x;
    __bf16* base = h + (size_t)row * 4224;
    const __bf16* lnr = ln + (size_t)row * 1088;
    const __bf16* B0 = Bt + (size_t)4096 * 1088;
    const __bf16* B1 = Bt + (size_t)4097 * 1088;
    const __bf16* B2 = Bt + (size_t)4098 * 1088;
    __shared__ float sb[4];
    float d0 = 0.f, d1 = 0.f, d2 = 0.f;
    for (int i = threadIdx.x; i < 1088; i += 256) {
        float a = (float)lnr[i];
        d0 += a * (float)B0[i];
        d1 += a * (float)B1[i];
        d2 += a * (float)B2[i];
    }
    d0 = blockSum256(d0, sb);
    d1 = blockSum256(d1, sb);
    d2 = blockSum256(d2, sb);
    float t3[3] = {d0 + bias[4096], d1 + bias[4097], d2 + bias[4098]};
    float ssq_t = 0.f;
#pragma unroll
    for (int j = 0; j < 3; j++) {
        float v = gelu_f(t3[j]);
        t3[j] = v; ssq_t += v * v;
    }
    if (threadIdx.x == 0) {
        base[1 + 4096] = (__bf16)t3[0];
        base[1 + 4097] = (__bf16)t3[1];
        base[1 + 4098] = (__bf16)t3[2];
    }
    float s = 0.f;
    for (int i = threadIdx.x; i < 4096; i += 256) { float t = (float)base[1 + i]; s += t * t; }
    s = blockSum256(s, sb) + ssq_t;
    if (threadIdx.x == 0) base[0] = (__bf16)sqrtf(expf(*curv) + s);
    if (threadIdx.x < 124) base[4100 + threadIdx.x] = (__bf16)0.f;  // zero pad 4100..4223
}

// ---------------------------------------------------------------- weight convert + transpose
__global__ __launch_bounds__(256) void wt_k(
    const float* __restrict__ W, int K, int N,
    __bf16* __restrict__ Wt, int Kp)
{
    __shared__ float s[32][33];
    int tx = threadIdx.x & 31, ty = threadIdx.x >> 5;    // 32 x 8
    int k0 = blockIdx.x * 32, n0 = blockIdx.y * 32;
#pragma unroll
    for (int r = 0; r < 4; r++) {
        int k = k0 + ty + 8 * r, n = n0 + tx;
        s[ty + 8 * r][tx] = (k < K && n < N) ? W[(size_t)k * N + n] : 0.f;
    }
    __syncthreads();
#pragma unroll
    for (int r = 0; r < 4; r++) {
        int n = n0 + ty + 8 * r, k = k0 + tx;
        if (n < N) Wt[(size_t)n * Kp + k] = (__bf16)s[tx][ty + 8 * r];
    }
}

// ---------------------------------------------------------------- bf16 MFMA GEMM 256x256, BK=64, 4-phase
// XCD-chunked block remap: lin=(by*gx+bx); xcd=lin&7 (HW round-robin), XCDs
// tiled 4(m)x2(n), within-XCD n-fastest. All sharers of an A K-slice (LN
// blocks) and of a B K-slice (LM blocks) are co-XCD -> one L2 fill each.
// Requires gridDim.y%4==0 && gridDim.x%2==0.
template<bool BIAS, bool GELU, bool OUTBF>
__global__ __launch_bounds__(512, 2) void mgemm256_k(
    const __bf16* __restrict__ A, int lda,
    const __bf16* __restrict__ Bt, int ldb, int NB,   // NB = valid rows of Bt (row clamp)
    const float* __restrict__ bias,
    void* __restrict__ Cout, int ldc,
    int N, int Kp)                                     // Kp multiple of 64
{
    __shared__ __bf16 sAB[65536];   // [A db0 |A db1 |B db0 |B db1] x 16384 elems
    const int tid = threadIdx.x;
    const int w = tid >> 6, lane = tid & 63;
    const int wm = w >> 2, wn = w & 3;
    const int lr = lane & 15, lq = lane >> 4;

    const int lin = blockIdx.y * gridDim.x + blockIdx.x;
    const int xcd = lin & 7, loc = lin >> 3;
    const int LN = gridDim.x >> 1, LM = gridDim.y >> 2;
    const int mt = (xcd >> 1) * LM + loc / LN;
    const int nt = (xcd & 1) * LN + loc % LN;
    const int m0 = mt * 256, n0 = nt * 256;

    const int rr  = tid >> 3;
    const int csw = ((tid & 7) ^ (rr & 7)) << 3;   // elems
    const __bf16* gA[4]; const __bf16* gB[4];
#pragma unroll
    for (int c = 0; c < 4; c++) {
        gA[c] = A + (size_t)(m0 + c * 64 + rr) * lda + csw;
        int rb = n0 + c * 64 + rr; rb = (rb < NB) ? rb : (NB - 1);
        gB[c] = Bt + (size_t)rb * ldb + csw;
    }
    __bf16* lA = sAB + (w << 9);            // + db*16384 + c*4096
    __bf16* lB = sAB + 32768 + (w << 9);

    const int off0 = (lq * 8) ^ ((lr & 7) << 3);
    const int off1 = off0 ^ 32;
    const int arow = wm * 128 + lr;
    const int brow = wn * 64 + lr;

    f32x4 zero = {0.f, 0.f, 0.f, 0.f};
    f32x4 acc[8][4];
#pragma unroll
    for (int i = 0; i < 8; i++)
#pragma unroll
        for (int j = 0; j < 4; j++) acc[i][j] = zero;

    // prologue: stage K-tile 0 -> db0
#pragma unroll
    for (int c = 0; c < 4; c++) {
        g2l16(gA[c], lA + c * 4096);
        g2l16(gB[c], lB + c * 4096);
    }
    asm volatile("s_waitcnt vmcnt(0)" ::: "memory");
    __builtin_amdgcn_s_barrier();

    const int NT = Kp >> 6;
    for (int kt = 0; kt < NT; ++kt) {
        const int cur = kt & 1;
        const __bf16* pA = sAB + cur * 16384;
        const __bf16* pB = sAB + 32768 + cur * 16384;
        bf16x8 af[4][2], bfr[4][2];

        // ---- phase 1: issue next-tile stage early; read A half0 + B[0..1]; MFMA q00
        if (kt + 1 < NT) {
            const int ko = (kt + 1) << 6;
            __bf16* dA = lA + (cur ^ 1) * 16384;
            __bf16* dB = lB + (cur ^ 1) * 16384;
#pragma unroll
            for (int c = 0; c < 4; c++) {
                g2l16(gA[c] + ko, dA + c * 4096);
                g2l16(gB[c] + ko, dB + c * 4096);
            }
        }
#pragma unroll
        for (int i = 0; i < 4; i++) {
            const __bf16* r = pA + (arow + i * 16) * 64;
            af[i][0] = *(const bf16x8*)(r + off0);
            af[i][1] = *(const bf16x8*)(r + off1);
        }
#pragma unroll
        for (int j = 0; j < 2; j++) {
            const __bf16* r = pB + (brow + j * 16) * 64;
            bfr[j][0] = *(const bf16x8*)(r + off0);
            bfr[j][1] = *(const bf16x8*)(r + off1);
        }
        __builtin_amdgcn_s_barrier();
        __builtin_amdgcn_s_setprio(1);
#pragma unroll
        for (int ks = 0; ks < 2; ks++)
#pragma unroll
            for (int i = 0; i < 4; i++)
#pragma unroll
                for (int j = 0; j < 2; j++)
                    acc[i][j] = __builtin_amdgcn_mfma_f32_16x16x32_bf16(af[i][ks], bfr[j][ks], acc[i][j], 0, 0, 0);
        __builtin_amdgcn_s_setprio(0);
        __builtin_amdgcn_s_barrier();

        // ---- phase 2: read B[2..3]; MFMA q01
#pragma unroll
        for (int j = 2; j < 4; j++) {
            const __bf16* r = pB + (brow + j * 16) * 64;
            bfr[j][0] = *(const bf16x8*)(r + off0);
            bfr[j][1] = *(const bf16x8*)(r + off1);
        }
        __builtin_amdgcn_s_barrier();
        __builtin_amdgcn_s_setprio(1);
#pragma unroll
        for (int ks = 0; ks < 2; ks++)
#pragma unroll
            for (int i = 0; i < 4; i++)
#pragma unroll
                for (int j = 2; j < 4; j++)
                    acc[i][j] = __builtin_amdgcn_mfma_f32_16x16x32_bf16(af[i][ks], bfr[j][ks], acc[i][j], 0, 0, 0);
        __builtin_amdgcn_s_setprio(0);
        __builtin_amdgcn_s_barrier();

        // ---- phase 3: read A half1 (reuse af regs); MFMA q10
#pragma unroll
        for (int i = 0; i < 4; i++) {
            const __bf16* r = pA + (arow + 64 + i * 16) * 64;
            af[i][0] = *(const bf16x8*)(r + off0);
            af[i][1] = *(const bf16x8*)(r + off1);
        }
        __builtin_amdgcn_s_barrier();
        __builtin_amdgcn_s_setprio(1);
#pragma unroll
        for (int ks = 0; ks < 2; ks++)
#pragma unroll
            for (int i = 0; i < 4; i++)
#pragma unroll
                for (int j = 0; j < 2; j++)
                    acc[4 + i][j] = __builtin_amdgcn_mfma_f32_16x16x32_bf16(af[i][ks], bfr[j][ks], acc[4 + i][j], 0, 0, 0);
        __builtin_amdgcn_s_setprio(0);
        __builtin_amdgcn_s_barrier();

        // ---- phase 4: MFMA q11; tile boundary (the ONLY vmcnt wait per tile)
        __builtin_amdgcn_s_setprio(1);
#pragma unroll
        for (int ks = 0; ks < 2; ks++)
#pragma unroll
            for (int i = 0; i < 4; i++)
#pragma unroll
                for (int j = 2; j < 4; j++)
                    acc[4 + i][j] = __builtin_amdgcn_mfma_f32_16x16x32_bf16(af[i][ks], bfr[j][ks], acc[4 + i][j], 0, 0, 0);
        __builtin_amdgcn_s_setprio(0);
        asm volatile("s_waitcnt vmcnt(0) lgkmcnt(0)" ::: "memory");
        __builtin_amdgcn_s_barrier();
    }

    // ---- epilogue
#pragma unroll
    for (int j = 0; j < 4; j++) {
        const int n = n0 + wn * 64 + j * 16 + lr;
        if (n < N) {
            const float bv = BIAS ? bias[n] : 0.f;
#pragma unroll
            for (int i = 0; i < 8; i++) {
#pragma unroll
                for (int r = 0; r < 4; r++) {
                    const int m = m0 + wm * 128 + i * 16 + lq * 4 + r;
                    float v = acc[i][j][r] + bv;
                    if (GELU) v = gelu_f(v);
                    if (OUTBF) ((__bf16*)Cout)[(size_t)m * ldc + n] = (__bf16)v;
                    else       ((float*)Cout)[(size_t)m * ldc + n] = v;
                }
            }
        }
    }
}

// ---------------------------------------------------------------- bf16 MFMA GEMM 128x128, BK=64, pipelined
template<bool BIAS, bool GELU, bool SKIP>
__global__ __launch_bounds__(256, 2) void mgemm128_k(
    const __bf16* __restrict__ A, int lda,
    const __bf16* __restrict__ Bt, int ldb,
    const float* __restrict__ bias,
    const float* __restrict__ skip, int ldskip,
    float* __restrict__ Cout, int ldc,
    int N, int Kp)                                     // Kp multiple of 64; N=1024, grid 256
{
    __shared__ __bf16 sAB[32768];   // [A db0 |A db1 |B db0 |B db1] x 8192 elems
    const int tid = threadIdx.x;
    const int w = tid >> 6, lane = tid & 63;
    const int wm = w >> 1, wn = w & 1;
    const int lr = lane & 15, lq = lane >> 4;

    // bijective XCD swizzle: XCD k gets swz in [k*cpx, (k+1)*cpx) -> 4 contiguous m-panels
    const int bid = blockIdx.x;
    const int cpx = gridDim.x >> 3;                 // 32
    const int swz = (bid & 7) * cpx + (bid >> 3);
    const int m0 = (swz >> 3) * 128, n0 = (swz & 7) * 128;

    const int rr  = tid >> 3;
    const int csw = ((tid & 7) ^ (rr & 7)) << 3;
    const __bf16* gA[4]; const __bf16* gB[4];
#pragma unroll
    for (int c = 0; c < 4; c++) {
        gA[c] = A + (size_t)(m0 + c * 32 + rr) * lda + csw;
        gB[c] = Bt + (size_t)(n0 + c * 32 + rr) * ldb + csw;
    }
    __bf16* lA = sAB + (w << 9);            // + db*8192 + c*2048
    __bf16* lB = sAB + 16384 + (w << 9);

    const int off0 = (lq * 8) ^ ((lr & 7) << 3);
    const int off1 = off0 ^ 32;
    const int arow = wm * 64 + lr;
    const int brow = wn * 64 + lr;

    f32x4 zero = {0.f, 0.f, 0.f, 0.f};
    f32x4 acc[4][4];
#pragma unroll
    for (int i = 0; i < 4; i++)
#pragma unroll
        for (int j = 0; j < 4; j++) acc[i][j] = zero;

    // prologue: stage K-tile 0 -> db0
#pragma unroll
    for (int c = 0; c < 4; c++) {
        g2l16(gA[c], lA + c * 2048);
        g2l16(gB[c], lB + c * 2048);
    }
    asm volatile("s_waitcnt vmcnt(0)" ::: "memory");
    __builtin_amdgcn_s_barrier();

    const int NT = Kp >> 6;
    for (int kt = 0; kt < NT; ++kt) {
        const int cur = kt & 1;
        const __bf16* pA = sAB + cur * 8192;
        const __bf16* pB = sAB + 16384 + cur * 8192;
        bf16x8 af[4][2], bfr[4][2];

        // ---- phase 1: issue next-tile stage; read all A + B[0..1]; 16 MFMA (j=0,1)
        if (kt + 1 < NT) {
            const int ko = (kt + 1) << 6;
            __bf16* dA = lA + (cur ^ 1) * 8192;
            __bf16* dB = lB + (cur ^ 1) * 8192;
#pragma unroll
            for (int c = 0; c < 4; c++) {
                g2l16(gA[c] + ko, dA + c * 2048);
                g2l16(gB[c] + ko, dB + c * 2048);
            }
        }
#pragma unroll
        for (int i = 0; i < 4; i++) {
            const __bf16* r = pA + (arow + i * 16) * 64;
            af[i][0] = *(const bf16x8*)(r + off0);
            af[i][1] = *(const bf16x8*)(r + off1);
        }
#pragma unroll
        for (int j = 0; j < 2; j++) {
            const __bf16* r = pB + (brow + j * 16) * 64;
            bfr[j][0] = *(const bf16x8*)(r + off0);
            bfr[j][1] = *(const bf16x8*)(r + off1);
        }
        __builtin_amdgcn_s_barrier();
        __builtin_amdgcn_s_setprio(1);
#pragma unroll
        for (int ks = 0; ks < 2; ks++)
#pragma unroll
            for (int i = 0; i < 4; i++)
#pragma unroll
                for (int j = 0; j < 2; j++)
                    acc[i][j] = __builtin_amdgcn_mfma_f32_16x16x32_bf16(af[i][ks], bfr[j][ks], acc[i][j], 0, 0, 0);
        __builtin_amdgcn_s_setprio(0);
        __builtin_amdgcn_s_barrier();

        // ---- phase 2: read B[2..3]; 16 MFMA (j=2,3); tile boundary
#pragma unroll
        for (int j = 2; j < 4; j++) {
            const __bf16* r = pB + (brow + j * 16) * 64;
            bfr[j][0] = *(const bf16x8*)(r + off0);
            bfr[j][1] = *(const bf16x8*)(r + off1);
        }
        __builtin_amdgcn_s_barrier();
        __builtin_amdgcn_s_setprio(1);
#pragma unroll
        for (int ks = 0; ks < 2; ks++)
#pragma unroll
            for (int i = 0; i < 4; i++)
#pragma unroll
                for (int j = 2; j < 4; j++)
                    acc[i][j] = __builtin_amdgcn_mfma_f32_16x16x32_bf16(af[i][ks], bfr[j][ks], acc[i][j], 0, 0, 0);
        __builtin_amdgcn_s_setprio(0);
        asm volatile("s_waitcnt vmcnt(0) lgkmcnt(0)" ::: "memory");
        __builtin_amdgcn_s_barrier();
    }

    // ---- epilogue
#pragma unroll
    for (int j = 0; j < 4; j++) {
        const int n = n0 + wn * 64 + j * 16 + lr;
        if (n < N) {
            const float bv = BIAS ? bias[n] : 0.f;
#pragma unroll
            for (int i = 0; i < 4; i++) {
#pragma unroll
                for (int r = 0; r < 4; r++) {
                    const int m = m0 + wm * 64 + i * 16 + lq * 4 + r;
                    float v = acc[i][j][r] + bv;
                    if (GELU) v = gelu_f(v);
                    if (SKIP) v += skip[(size_t)m * ldskip + n];
                    Cout[(size_t)m * ldc + n] = v;
                }
            }
        }
    }
}

// ---------------------------------------------------------------- RoPE in-place(q) + Kb bf16 + q/k norms
__global__ __launch_bounds__(256) void rope_k(
    float* __restrict__ QKV, const float* __restrict__ curv,
    float* __restrict__ qt, float* __restrict__ kt,
    __bf16* __restrict__ Kb, __bf16* __restrict__ Obf)
{
    int row = blockIdx.x;              // b*T + t
    int b = row >> 11, t = row & (TT - 1);
    int wv = threadIdx.x >> 6, d = threadIdx.x & 63;
    int j = d & 31;
    float fr = (float)t * powf(10000.0f, -(float)(2 * j) / 64.0f);
    float cv = cosf(fr), sv = sinf(fr);
    float sgn = (d < 32) ? sv : -sv;
    for (int h = wv; h < HH; h += 4) {
        float Kh = expf(curv[h]);
        float* base = QKV + (size_t)row * 3072 + h * 64;
        float q = base[d], k = base[1024 + d];
        float qp = __shfl_xor(q, 32);
        float kp = __shfl_xor(k, 32);
        float qr = q * cv + qp * sgn;
        float kr = k * cv + kp * sgn;
        base[d] = qr;                         // q roped in place (fp32 for hi/lo split)
        size_t oidx = ((size_t)(b * HH + h) * TT + t);
        Kb[oidx * 64 + d] = (__bf16)kr;       // roped k, bf16 head-major
        float sq = qr * qr, sk = kr * kr;
#pragma unroll
        for (int o = 32; o; o >>= 1) {
            sq += __shfl_xor(sq, o);
            sk += __shfl_xor(sk, o);
        }
        if (d == 0) {
            qt[oidx] = sqrtf(Kh + sq);
            kt[oidx] = sqrtf(Kh + sk);
        }
    }
    if (threadIdx.x < 48) Obf[(size_t)row * 1088 + 1040 + threadIdx.x] = (__bf16)0.f;
}

// ---------------------------------------------------------------- V transpose -> Vtb bf16 [bh][d][t] + vt norms
__global__ __launch_bounds__(256) void vtrans_k(
    const float* __restrict__ QKV, const float* __restrict__ curv,
    __bf16* __restrict__ Vtb, float* __restrict__ vt)
{
    __shared__ float sT[64 * 65];
    int bh = blockIdx.y; int h = bh & (HH - 1); int b = bh >> 4;
    int t0 = blockIdx.x * 64;
    int tid = threadIdx.x, w = tid >> 6, lane = tid & 63;
    float Kh = expf(curv[h]);
    const float* vbase = QKV + (size_t)(b * TT + t0) * 3072 + 2048 + h * 64;
#pragma unroll 4
    for (int i = 0; i < 16; i++) {
        int tr = w * 16 + i;
        float v = vbase[(size_t)tr * 3072 + lane];
        sT[lane * 65 + tr] = v;
        float s = v * v;
#pragma unroll
        for (int o = 32; o; o >>= 1) s += __shfl_xor(s, o);
        if (lane == 0) vt[(size_t)bh * TT + t0 + tr] = sqrtf(Kh + s);
    }
    __syncthreads();
    int d = tid >> 2, seg = tid & 3;
    const float* r = &sT[d * 65 + seg * 16];
    bf16x8 o0, o1;
#pragma unroll
    for (int i = 0; i < 8; i++) { o0[i] = (__bf16)r[i]; o1[i] = (__bf16)r[8 + i]; }
    __bf16* dst = Vtb + ((size_t)bh * 64 + d) * TT + t0 + seg * 16;
    *(bf16x8*)dst = o0;
    *(bf16x8*)(dst + 8) = o1;
}

// ---------------------------------------------------------------- MFMA flash hyperbolic attention (v6)
__global__ __launch_bounds__(256, 4) void flash_k(
    const float* __restrict__ QKV,
    const __bf16* __restrict__ Kb, const __bf16* __restrict__ Vtb,
    const float* __restrict__ qt, const float* __restrict__ kt,
    const float* __restrict__ vt,
    const float* __restrict__ curv,
    __bf16* __restrict__ O)
{
    __shared__ __bf16 sK[4096];     // [ksp][quad][s=64][8 d]
    __shared__ __bf16 sVt[4096];    // [ksp][quad][d=64][8 s]
    __shared__ __bf16 sP[4 * 16 * 72];
    __shared__ float skt[64], svt[64];

    int bh = blockIdx.x; int h = bh & (HH - 1); int b = bh >> 4;
    int pi = blockIdx.y;                   // pair index 0..31
    float Kh = expf(curv[h]);
    float sqKh = sqrtf(Kh), msqK = -sqKh, invKh = 1.0f / Kh;
    const float* tok = QKV + (size_t)b * TT * 3072 + h * 64;  // roped q fp32
    const char* KbB = (const char*)Kb + (size_t)bh * TT * 128;
    const char* VtB = (const char*)Vtb + (size_t)bh * 64 * (TT * 2);
    const float* qtp = qt + (size_t)bh * TT;
    const float* ktp = kt + (size_t)bh * TT;
    const float* vtp = vt + (size_t)bh * TT;

    int tid = threadIdx.x;
    int w = tid >> 6, lane = tid & 63;
    int m = lane & 15, quad = lane >> 4;
    int qA = pi * 32, qB = (63 - pi) * 32;
    int myBase = (w < 2) ? (qA + 16 * w) : (qB + 16 * (w - 2));
    int myJmax = (myBase + 15) >> 6;
    int blockJmax = (qB + 31) >> 6;
    __bf16* sPw = &sP[w * 16 * 72];

    // Q fragments (hi + lo bf16), A-layout: A[m][k=quad*8+j+32*ks]
    bf16x8 qhi[2], qlo[2];
    {
        const float* qrow = tok + (size_t)(myBase + m) * 3072;
#pragma unroll
        for (int ks = 0; ks < 2; ks++) {
            const float* s = qrow + quad * 8 + 32 * ks;
            float4 f0 = *(const float4*)s;
            float4 f1 = *(const float4*)(s + 4);
            float fa[8] = {f0.x, f0.y, f0.z, f0.w, f1.x, f1.y, f1.z, f1.w};
#pragma unroll
            for (int jj = 0; jj < 8; jj++) {
                __bf16 hv = (__bf16)fa[jj];
                qhi[ks][jj] = hv;
                qlo[ks][jj] = (__bf16)(fa[jj] - (float)hv);
            }
        }
    }
    float qtv[4]; int qg[4];
#pragma unroll
    for (int r = 0; r < 4; r++) { qg[r] = myBase + quad * 4 + r; qtv[r] = qtp[qg[r]]; }

    f32x4 zero = {0.f, 0.f, 0.f, 0.f};
    f32x4 accO[4];
#pragma unroll
    for (int nt = 0; nt < 4; nt++) accO[nt] = zero;
    float lsumr[4] = {}, o0r[4] = {};

    char* sKb  = (char*)sK  + w * 1024;
    char* sVb  = (char*)sVt + w * 1024;

    for (int j = 0; j <= blockJmax; ++j) {
        int sb = j << 6;
        __syncthreads();
        // ---- stage K/V tiles: 4 pure g2l16 per thread ----
        {
            const char* kg = KbB + (size_t)(sb + lane) * 128 + w * 16;
            g2l16(kg,      sKb);
            g2l16(kg + 64, sKb + 4096);
            const char* vg = VtB + (size_t)lane * (TT * 2) + sb * 2 + w * 16;
            g2l16(vg,      sVb);
            g2l16(vg + 64, sVb + 4096);
        }
        if (tid < 64) skt[tid] = ktp[sb + tid];
        else if (tid < 128) svt[tid - 64] = vtp[sb + tid - 64];
        __syncthreads();

        if (j > myJmax) continue;

        // ---- QK^T: S[16 x 64] ----
        f32x4 accS[4];
#pragma unroll
        for (int nt = 0; nt < 4; nt++) accS[nt] = zero;
#pragma unroll
        for (int nt = 0; nt < 4; nt++) {
#pragma unroll
            for (int ksp = 0; ksp < 2; ksp++) {
                bf16x8 bk = *(const bf16x8*)&sK[((ksp * 4 + quad) * 64 + nt * 16 + m) * 8];
                accS[nt] = __builtin_amdgcn_mfma_f32_16x16x32_bf16(qhi[ksp], bk, accS[nt], 0, 0, 0);
                accS[nt] = __builtin_amdgcn_mfma_f32_16x16x32_bf16(qlo[ksp], bk, accS[nt], 0, 0, 0);
            }
        }
        // ---- score epilogue: hyperbolic logit -> p, raw transcendentals ----
#pragma unroll
        for (int nt = 0; nt < 4; nt++) {
            int col = nt * 16 + m;
            int sglob = sb + col;
            float ktv = skt[col], vtv = svt[col];
#pragma unroll
            for (int r = 0; r < 4; r++) {
                float dot = accS[nt][r];
                float rdiff = fmaf(qtv[r], ktv, -dot);          // qt*kt - q.k
                float ratio = fmaxf(rdiff * invKh, 1.0f + 1e-7f);
                float y = ratio + fsqrt_(fmaf(ratio, ratio, -1.0f));
                float pv = fexp2(msqK * flog2(y));              // exp(-sqrt(K)*acosh)
                float p = (sglob <= qg[r]) ? pv : 0.0f;
                lsumr[r] += p;
                o0r[r] = fmaf(p, vtv, o0r[r]);
                sPw[(quad * 4 + r) * 72 + col] = (__bf16)p;
            }
        }
        __asm__ volatile("s_waitcnt lgkmcnt(0)" ::: "memory");
        // ---- PV: O += P @ V ----
#pragma unroll
        for (int ksp = 0; ksp < 2; ksp++) {
            bf16x8 aP = *(const bf16x8*)&sPw[m * 72 + ksp * 32 + quad * 8];
#pragma unroll
            for (int nt = 0; nt < 4; nt++) {
                bf16x8 bV = *(const bf16x8*)&sVt[((ksp * 4 + quad) * 64 + nt * 16 + m) * 8];
                accO[nt] = __builtin_amdgcn_mfma_f32_16x16x32_bf16(aP, bV, accO[nt], 0, 0, 0);
            }
        }
    }

    // ---- final: reduce lsum/o0 over the 16 col-lanes, normalize, write ----
#pragma unroll
    for (int r = 0; r < 4; r++) {
#pragma unroll
        for (int off = 1; off < 16; off <<= 1) {
            lsumr[r] += __shfl_xor(lsumr[r], off);
            o0r[r]   += __shfl_xor(o0r[r], off);
        }
    }
#pragma unroll
    for (int r = 0; r < 4; r++) {
        float inv = frcp_(lsumr[r]);
        float o0f = o0r[r] * inv;
        float ov[4]; float part = 0.f;
#pragma unroll
        for (int nt = 0; nt < 4; nt++) { float t = accO[nt][r] * inv; ov[nt] = t; part += t * t; }
        part += __shfl_xor(part, 1);
        part += __shfl_xor(part, 2);
        part += __shfl_xor(part, 4);
        part += __shfl_xor(part, 8);
        float scale = sqKh * frsq_(fmaxf(o0f * o0f - part, 1e-12f));
        size_t orow = (size_t)(b * TT + qg[r]) * 1088 + h * 65;
        if (m == 0) O[orow] = (__bf16)(o0f * scale);
#pragma unroll
        for (int nt = 0; nt < 4; nt++) O[orow + 1 + nt * 16 + m] = (__bf16)(ov[nt] * scale);
    }
}

// ---------------------------------------------------------------- launch
extern "C" void kernel_launch(void* const* d_in, const int* in_sizes, int n_in,
                              void* d_out, int out_size, void* d_ws, size_t ws_size,
                              hipStream_t stream) {
    const float* x    = (const float*)d_in[0];
    const float* bc   = (const float*)d_in[1];
    const float* mc   = (const float*)d_in[2];
    const float* ac   = (const float*)d_in[3];
    const float* w_qkv = (const float*)d_in[4];
    const float* w_ap  = (const float*)d_in[5];
    const float* b_ap  = (const float*)d_in[6];
    const float* w_me  = (const float*)d_in[7];
    const float* b_me  = (const float*)d_in[8];
    const float* w_ms  = (const float*)d_in[9];
    const float* b_ms  = (const float*)d_in[10];
    const float* lnw  = (const float*)d_in[11];
    const float* lnb  = (const float*)d_in[12];
    float* out = (float*)d_out;
    float* ws  = (float*)d_ws;

    // workspace (floats), total ~96.5 MB.
    float* R      = ws;
    float* qkvbuf = R;                             // M*3072 fp32 (dead after flash)
    float* X2     = R;                             // M*1024 fp32 (written step 5)
    __bf16* h_bf  = (__bf16*)(R + 4194304);        // M*4224 bf16 -> ends 12,845,056
    float* p      = R + 12845056;
    __bf16* ln_bf = (__bf16*)p;  p += 2228224;     // M*1088 bf16
    __bf16* o_bf  = (__bf16*)p;  p += 2228224;     // M*1088 bf16
    __bf16* qkvT  = (__bf16*)p;  p += 1671168;     // 3072*1088 bf16
    __bf16* apT   = (__bf16*)p;  p += 557056;      // 1024*1088 bf16
    float*  meT_f = p;           p += 2229856;     // 4099*1088 bf16 (after flash)
    float*  msT_f = p;           p += 2162688;     // 1024*4224 bf16 (after flash)
    float* Qt = p;               p += 2 * HH * TT;
    float* Kt = p;               p += 2 * HH * TT;
    float* Vt = p;
    __bf16* meT = (__bf16*)meT_f;
    __bf16* msT = (__bf16*)msT_f;
    __bf16* Kb  = (__bf16*)meT_f;   // 32*2048*64 bf16 <= meT slot; dead before wt_k(meT)
    __bf16* Vtb = (__bf16*)msT_f;   // same size      <= msT slot; dead before wt_k(msT)

    // 0. weight transposes needed before flash (zero-filled past K)
    wt_k<<<dim3(34, 96),  256, 0, stream>>>(w_qkv, 1025, 3072, qkvT, 1088);
    wt_k<<<dim3(34, 32),  256, 0, stream>>>(w_ap,  1040, 1024, apT,  1088);

    // 1. ln1 = block_norm(project(x)) -> bf16 (stride 1088, zero pad)
    block_norm_bf_k<<<MM, 256, 0, stream>>>(x, 1024, ln_bf, 1088, lnw, lnb, bc);
    // 2. qkv = ln1 @ w_qkv -> fp32 (M,3072)   [256^2, XCD-chunked]
    mgemm256_k<false, false, false><<<dim3(12, 16), 512, 0, stream>>>(
        ln_bf, 1088, qkvT, 1088, 3072, nullptr, qkvbuf, 3072, 3072, 1088);
    // 3a. RoPE (q in place fp32, Kb bf16) + q/k norms + o_bf pad (cols 1040..1087)
    rope_k<<<MM, 256, 0, stream>>>(qkvbuf, ac, Qt, Kt, Kb, o_bf);
    // 3b. V transpose -> Vtb bf16 + v norms
    vtrans_k<<<dim3(32, 32), 256, 0, stream>>>(qkvbuf, ac, Vtb, Vt);
    // 4. MFMA flash attention -> o_t bf16 (M,1088)
    flash_k<<<dim3(2 * HH, 32), 256, 0, stream>>>(qkvbuf, Kb, Vtb, Qt, Kt, Vt, ac, o_bf);
    // 0b. remaining weight transposes (into the slots Kb/Vtb just vacated)
    wt_k<<<dim3(34, 129), 256, 0, stream>>>(w_me,  1025, 4099, meT, 1088);
    wt_k<<<dim3(132, 32), 256, 0, stream>>>(w_ms,  4100, 1024, msT, 4224);
    // 5. lx2[...,1:] = x + o_t @ w_attn_proj + b -> X2 fp32   [128^2 pipelined]
    mgemm128_k<true, false, true><<<dim3(256), 256, 0, stream>>>(
        o_bf, 1088, apT, 1088, b_ap, x, 1024, X2, 1024, 1024, 1088);
    // 6. ln2 = block_norm(lx2) -> bf16
    block_norm_bf_k<<<MM, 256, 0, stream>>>(X2, 1024, ln_bf, 1088, lnw, lnb, bc);
    // 7. h[1..4096] = gelu(ln2 @ w_mlp_expand + b) -> bf16   [256^2, XCD-chunked, exact 16x16]
    mgemm256_k<true, true, true><<<dim3(16, 16), 512, 0, stream>>>(
        ln_bf, 1088, meT, 1088, 4099, b_me, (void*)(h_bf + 1), 4224, 4099, 1088);
    // 8. h cols 4097..4099 (ragged tail vs meT rows 4096..4098) + x0 + pad
    row_x0_tail_k<<<MM, 256, 0, stream>>>(h_bf, ln_bf, meT, b_me, mc);
    // 9. out[...,1:] = lx2[...,1:] + h @ w_mlp_shrink + b   [128^2 pipelined]
    mgemm128_k<true, false, true><<<dim3(256), 256, 0, stream>>>(
        h_bf, 4224, msT, 4224, b_ms, X2, 1024, out + 1, 1025, 1024, 4224);
    // 10. out[...,0]
    row_x0_k<<<MM, 256, 0, stream>>>(out, 1025, 1024, bc);
}

// Round 5
// 444.444 us; speedup vs baseline: 1.1964x; 1.0204x over previous
//
#include <hip/hip_runtime.h>
#include <math.h>

// Problem constants: B=2, T=2048, E=1024, H=16, D=64; M = B*T = 4096
#define MM   4096
#define TT   2048
#define HH   16

typedef __bf16 bf16x8 __attribute__((ext_vector_type(8)));
typedef float f32x4 __attribute__((ext_vector_type(4)));

// async global->LDS, 16B per lane; LDS dest = wave-uniform base + lane*16
__device__ __forceinline__ void g2l16(const void* g, void* l) {
    __builtin_amdgcn_global_load_lds(
        (__attribute__((address_space(1))) void*)g,
        (__attribute__((address_space(3))) void*)l, 16, 0, 0);
}

// ---- raw transcendentals (guarded; libm fallback). Without -ffast-math the
// libm versions lower to multi-instruction OCML guard sequences — 3-4x cost.
#if __has_builtin(__builtin_amdgcn_exp2f)
__device__ __forceinline__ float fexp2(float x) { return __builtin_amdgcn_exp2f(x); }
#else
__device__ __forceinline__ float fexp2(float x) { return exp2f(x); }
#endif
#if __has_builtin(__builtin_amdgcn_logf)
__device__ __forceinline__ float flog2(float x) { return __builtin_amdgcn_logf(x); }
#else
__device__ __forceinline__ float flog2(float x) { return log2f(x); }
#endif
#if __has_builtin(__builtin_amdgcn_sqrtf)
__device__ __forceinline__ float fsqrt_(float x) { return __builtin_amdgcn_sqrtf(x); }
#else
__device__ __forceinline__ float fsqrt_(float x) { return sqrtf(x); }
#endif
#if __has_builtin(__builtin_amdgcn_rcpf)
__device__ __forceinline__ float frcp_(float x) { return __builtin_amdgcn_rcpf(x); }
#else
__device__ __forceinline__ float frcp_(float x) { return 1.0f / x; }
#endif
#if __has_builtin(__builtin_amdgcn_rsqf)
__device__ __forceinline__ float frsq_(float x) { return __builtin_amdgcn_rsqf(x); }
#else
__device__ __forceinline__ float frsq_(float x) { return rsqrtf(x); }
#endif

// fast GELU (tanh form, abs err ~1e-3; ref tolerance 0.25 and downstream
// weights are 0.02-scale -> negligible). Replaces libm erff (~35 VALU ops).
__device__ __forceinline__ float gelu_f(float x) {
    float u = 0.7978845608028654f * fmaf(0.044715f * x, x * x, x);
    u = fminf(fmaxf(u, -15.f), 15.f);
    float t = fexp2(-2.885390081777927f * u);     // e^{-2u}
    return 0.5f * x * (1.f + (1.f - t) * frcp_(1.f + t));
}

// ---------------------------------------------------------------- reductions
__device__ __forceinline__ float blockSum256(float v, volatile float* sb) {
    int lane = threadIdx.x & 63, w = threadIdx.x >> 6;
#pragma unroll
    for (int o = 32; o; o >>= 1) v += __shfl_xor(v, o);
    if (lane == 0) sb[w] = v;
    __syncthreads();
    v = sb[0] + sb[1] + sb[2] + sb[3];
    __syncthreads();
    return v;
}

// ---------------------------------------------------------------- block_norm -> bf16 (ldo-wide, zero pad)
__global__ __launch_bounds__(256) void block_norm_bf_k(
    const float* __restrict__ in, int ld,
    __bf16* __restrict__ out, int ldo,
    const float* __restrict__ lw, const float* __restrict__ lb,
    const float* __restrict__ curv)
{
    int row = blockIdx.x;
    const float* x = in + (size_t)row * ld;
    __bf16* o = out + (size_t)row * ldo;
    __shared__ float sb[4];
    int tid = threadIdx.x;
    float v[4]; float s1 = 0.f, s2 = 0.f;
#pragma unroll
    for (int r = 0; r < 4; r++) {
        float t = x[tid + 256 * r];
        v[r] = t; s1 += t; s2 += t * t;
    }
    s1 = blockSum256(s1, sb);
    s2 = blockSum256(s2, sb);
    float mean = s1 * (1.f / 1024.f);
    float var  = s2 * (1.f / 1024.f) - mean * mean;
    float rs = rsqrtf(var + 1e-5f);
    float y[4]; float ssq = 0.f;
#pragma unroll
    for (int r = 0; r < 4; r++) {
        int i = tid + 256 * r;
        float t = (v[r] - mean) * rs * lw[i] + lb[i];
        y[r] = t; ssq += t * t;
    }
    ssq = blockSum256(ssq, sb);
#pragma unroll
    for (int r = 0; r < 4; r++) o[1 + tid + 256 * r] = (__bf16)y[r];
    if (tid == 0) o[0] = (__bf16)sqrtf(expf(*curv) + ssq);
    if (tid < ldo - 1025) o[1025 + tid] = (__bf16)0.f;   // zero pad cols 1025..ldo-1
}

// ---------------------------------------------------------------- row x0 (fp32, final output)
__global__ __launch_bounds__(256) void row_x0_k(
    float* __restrict__ buf, int stride, int n, const float* __restrict__ curv)
{
    int row = blockIdx.x;
    float* base = buf + (size_t)row * stride;
    __shared__ float sb[4];
    float s = 0.f;
    for (int i = threadIdx.x; i < n; i += 256) { float t = base[1 + i]; s += t * t; }
    s = blockSum256(s, sb);
    if (threadIdx.x == 0) base[0] = sqrtf(expf(*curv) + s);
}

// ---------------------------------------------------------------- h tail (3 ragged cols) + x0 + pad (stride 4224)
__global__ __launch_bounds__(256) void row_x0_tail_k(
    __bf16* __restrict__ h,
    const __bf16* __restrict__ ln,      // ln2, stride 1088 (zero-padded past 1025)
    const __bf16* __restrict__ Bt,      // meT, stride 1088
    const float* __restrict__ bias,     // b_me (4099)
    const float* __restrict__ curv)
{
    int row = blockIdx.x;
    __bf16* base = h + (size_t)row * 4224;
    const __bf16* lnr = ln + (size_t)row * 1088;
    const __bf16* B0 = Bt + (size_t)4096 * 1088;
    const __bf16* B1 = Bt + (size_t)4097 * 1088;
    const __bf16* B2 = Bt + (size_t)4098 * 1088;
    __shared__ float sb[4];
    float d0 = 0.f, d1 = 0.f, d2 = 0.f;
    for (int i = threadIdx.x; i < 1088; i += 256) {
        float a = (float)lnr[i];
        d0 += a * (float)B0[i];
        d1 += a * (float)B1[i];
        d2 += a * (float)B2[i];
    }
    d0 = blockSum256(d0, sb);
    d1 = blockSum256(d1, sb);
    d2 = blockSum256(d2, sb);
    float t3[3] = {d0 + bias[4096], d1 + bias[4097], d2 + bias[4098]};
    float ssq_t = 0.f;
#pragma unroll
    for (int j = 0; j < 3; j++) {
        float v = gelu_f(t3[j]);
        t3[j] = v; ssq_t += v * v;
    }
    if (threadIdx.x == 0) {
        base[1 + 4096] = (__bf16)t3[0];
        base[1 + 4097] = (__bf16)t3[1];
        base[1 + 4098] = (__bf16)t3[2];
    }
    float s = 0.f;
    for (int i = threadIdx.x; i < 4096; i += 256) { float t = (float)base[1 + i]; s += t * t; }
    s = blockSum256(s, sb) + ssq_t;
    if (threadIdx.x == 0) base[0] = (__bf16)sqrtf(expf(*curv) + s);
    if (threadIdx.x < 124) base[4100 + threadIdx.x] = (__bf16)0.f;  // zero pad 4100..4223
}

// ---------------------------------------------------------------- weight convert + transpose
__global__ __launch_bounds__(256) void wt_k(
    const float* __restrict__ W, int K, int N,
    __bf16* __restrict__ Wt, int Kp)
{
    __shared__ float s[32][33];
    int tx = threadIdx.x & 31, ty = threadIdx.x >> 5;    // 32 x 8
    int k0 = blockIdx.x * 32, n0 = blockIdx.y * 32;
#pragma unroll
    for (int r = 0; r < 4; r++) {
        int k = k0 + ty + 8 * r, n = n0 + tx;
        s[ty + 8 * r][tx] = (k < K && n < N) ? W[(size_t)k * N + n] : 0.f;
    }
    __syncthreads();
#pragma unroll
    for (int r = 0; r < 4; r++) {
        int n = n0 + ty + 8 * r, k = k0 + tx;
        if (n < N) Wt[(size_t)n * Kp + k] = (__bf16)s[tx][ty + 8 * r];
    }
}

// ---------------------------------------------------------------- bf16 MFMA GEMM 256x256, BK=64, 4-phase
// XCD-chunked block remap: lin=(by*gx+bx); xcd=lin&7 (HW round-robin), XCDs
// tiled 4(m)x2(n), within-XCD n-fastest. All sharers of an A K-slice (LN
// blocks) and of a B K-slice (LM blocks) are co-XCD -> one L2 fill each.
// Requires gridDim.y%4==0 && gridDim.x%2==0.
template<bool BIAS, bool GELU, bool OUTBF>
__global__ __launch_bounds__(512, 2) void mgemm256_k(
    const __bf16* __restrict__ A, int lda,
    const __bf16* __restrict__ Bt, int ldb, int NB,   // NB = valid rows of Bt (row clamp)
    const float* __restrict__ bias,
    void* __restrict__ Cout, int ldc,
    int N, int Kp)                                     // Kp multiple of 64
{
    __shared__ __bf16 sAB[65536];   // [A db0 |A db1 |B db0 |B db1] x 16384 elems
    const int tid = threadIdx.x;
    const int w = tid >> 6, lane = tid & 63;
    const int wm = w >> 2, wn = w & 3;
    const int lr = lane & 15, lq = lane >> 4;

    const int lin = blockIdx.y * gridDim.x + blockIdx.x;
    const int xcd = lin & 7, loc = lin >> 3;
    const int LN = gridDim.x >> 1, LM = gridDim.y >> 2;
    const int mt = (xcd >> 1) * LM + loc / LN;
    const int nt = (xcd & 1) * LN + loc % LN;
    const int m0 = mt * 256, n0 = nt * 256;

    const int rr  = tid >> 3;
    const int csw = ((tid & 7) ^ (rr & 7)) << 3;   // elems
    const __bf16* gA[4]; const __bf16* gB[4];
#pragma unroll
    for (int c = 0; c < 4; c++) {
        gA[c] = A + (size_t)(m0 + c * 64 + rr) * lda + csw;
        int rb = n0 + c * 64 + rr; rb = (rb < NB) ? rb : (NB - 1);
        gB[c] = Bt + (size_t)rb * ldb + csw;
    }
    __bf16* lA = sAB + (w << 9);            // + db*16384 + c*4096
    __bf16* lB = sAB + 32768 + (w << 9);

    const int off0 = (lq * 8) ^ ((lr & 7) << 3);
    const int off1 = off0 ^ 32;
    const int arow = wm * 128 + lr;
    const int brow = wn * 64 + lr;

    f32x4 zero = {0.f, 0.f, 0.f, 0.f};
    f32x4 acc[8][4];
#pragma unroll
    for (int i = 0; i < 8; i++)
#pragma unroll
        for (int j = 0; j < 4; j++) acc[i][j] = zero;

    // prologue: stage K-tile 0 -> db0
#pragma unroll
    for (int c = 0; c < 4; c++) {
        g2l16(gA[c], lA + c * 4096);
        g2l16(gB[c], lB + c * 4096);
    }
    asm volatile("s_waitcnt vmcnt(0)" ::: "memory");
    __builtin_amdgcn_s_barrier();

    const int NT = Kp >> 6;
    for (int kt = 0; kt < NT; ++kt) {
        const int cur = kt & 1;
        const __bf16* pA = sAB + cur * 16384;
        const __bf16* pB = sAB + 32768 + cur * 16384;
        bf16x8 af[4][2], bfr[4][2];

        // ---- phase 1: issue next-tile stage early; read A half0 + B[0..1]; MFMA q00
        if (kt + 1 < NT) {
            const int ko = (kt + 1) << 6;
            __bf16* dA = lA + (cur ^ 1) * 16384;
            __bf16* dB = lB + (cur ^ 1) * 16384;
#pragma unroll
            for (int c = 0; c < 4; c++) {
                g2l16(gA[c] + ko, dA + c * 4096);
                g2l16(gB[c] + ko, dB + c * 4096);
            }
        }
#pragma unroll
        for (int i = 0; i < 4; i++) {
            const __bf16* r = pA + (arow + i * 16) * 64;
            af[i][0] = *(const bf16x8*)(r + off0);
            af[i][1] = *(const bf16x8*)(r + off1);
        }
#pragma unroll
        for (int j = 0; j < 2; j++) {
            const __bf16* r = pB + (brow + j * 16) * 64;
            bfr[j][0] = *(const bf16x8*)(r + off0);
            bfr[j][1] = *(const bf16x8*)(r + off1);
        }
        __builtin_amdgcn_s_barrier();
        __builtin_amdgcn_s_setprio(1);
#pragma unroll
        for (int ks = 0; ks < 2; ks++)
#pragma unroll
            for (int i = 0; i < 4; i++)
#pragma unroll
                for (int j = 0; j < 2; j++)
                    acc[i][j] = __builtin_amdgcn_mfma_f32_16x16x32_bf16(af[i][ks], bfr[j][ks], acc[i][j], 0, 0, 0);
        __builtin_amdgcn_s_setprio(0);
        __builtin_amdgcn_s_barrier();

        // ---- phase 2: read B[2..3]; MFMA q01
#pragma unroll
        for (int j = 2; j < 4; j++) {
            const __bf16* r = pB + (brow + j * 16) * 64;
            bfr[j][0] = *(const bf16x8*)(r + off0);
            bfr[j][1] = *(const bf16x8*)(r + off1);
        }
        __builtin_amdgcn_s_barrier();
        __builtin_amdgcn_s_setprio(1);
#pragma unroll
        for (int ks = 0; ks < 2; ks++)
#pragma unroll
            for (int i = 0; i < 4; i++)
#pragma unroll
                for (int j = 2; j < 4; j++)
                    acc[i][j] = __builtin_amdgcn_mfma_f32_16x16x32_bf16(af[i][ks], bfr[j][ks], acc[i][j], 0, 0, 0);
        __builtin_amdgcn_s_setprio(0);
        __builtin_amdgcn_s_barrier();

        // ---- phase 3: read A half1 (reuse af regs); MFMA q10
#pragma unroll
        for (int i = 0; i < 4; i++) {
            const __bf16* r = pA + (arow + 64 + i * 16) * 64;
            af[i][0] = *(const bf16x8*)(r + off0);
            af[i][1] = *(const bf16x8*)(r + off1);
        }
        __builtin_amdgcn_s_barrier();
        __builtin_amdgcn_s_setprio(1);
#pragma unroll
        for (int ks = 0; ks < 2; ks++)
#pragma unroll
            for (int i = 0; i < 4; i++)
#pragma unroll
                for (int j = 0; j < 2; j++)
                    acc[4 + i][j] = __builtin_amdgcn_mfma_f32_16x16x32_bf16(af[i][ks], bfr[j][ks], acc[4 + i][j], 0, 0, 0);
        __builtin_amdgcn_s_setprio(0);
        __builtin_amdgcn_s_barrier();

        // ---- phase 4: MFMA q11; tile boundary (the ONLY vmcnt wait per tile)
        __builtin_amdgcn_s_setprio(1);
#pragma unroll
        for (int ks = 0; ks < 2; ks++)
#pragma unroll
            for (int i = 0; i < 4; i++)
#pragma unroll
                for (int j = 2; j < 4; j++)
                    acc[4 + i][j] = __builtin_amdgcn_mfma_f32_16x16x32_bf16(af[i][ks], bfr[j][ks], acc[4 + i][j], 0, 0, 0);
        __builtin_amdgcn_s_setprio(0);
        asm volatile("s_waitcnt vmcnt(0) lgkmcnt(0)" ::: "memory");
        __builtin_amdgcn_s_barrier();
    }

    // ---- epilogue
#pragma unroll
    for (int j = 0; j < 4; j++) {
        const int n = n0 + wn * 64 + j * 16 + lr;
        if (n < N) {
            const float bv = BIAS ? bias[n] : 0.f;
#pragma unroll
            for (int i = 0; i < 8; i++) {
#pragma unroll
                for (int r = 0; r < 4; r++) {
                    const int m = m0 + wm * 128 + i * 16 + lq * 4 + r;
                    float v = acc[i][j][r] + bv;
                    if (GELU) v = gelu_f(v);
                    if (OUTBF) ((__bf16*)Cout)[(size_t)m * ldc + n] = (__bf16)v;
                    else       ((float*)Cout)[(size_t)m * ldc + n] = v;
                }
            }
        }
    }
}

// ---------------------------------------------------------------- bf16 MFMA GEMM 128x128, BK=64, pipelined
template<bool BIAS, bool GELU, bool SKIP>
__global__ __launch_bounds__(256, 2) void mgemm128_k(
    const __bf16* __restrict__ A, int lda,
    const __bf16* __restrict__ Bt, int ldb,
    const float* __restrict__ bias,
    const float* __restrict__ skip, int ldskip,
    float* __restrict__ Cout, int ldc,
    int N, int Kp)                                     // Kp multiple of 64; N=1024, grid 256
{
    __shared__ __bf16 sAB[32768];   // [A db0 |A db1 |B db0 |B db1] x 8192 elems
    const int tid = threadIdx.x;
    const int w = tid >> 6, lane = tid & 63;
    const int wm = w >> 1, wn = w & 1;
    const int lr = lane & 15, lq = lane >> 4;

    // bijective XCD swizzle: XCD k gets swz in [k*cpx, (k+1)*cpx) -> 4 contiguous m-panels
    const int bid = blockIdx.x;
    const int cpx = gridDim.x >> 3;                 // 32
    const int swz = (bid & 7) * cpx + (bid >> 3);
    const int m0 = (swz >> 3) * 128, n0 = (swz & 7) * 128;

    const int rr  = tid >> 3;
    const int csw = ((tid & 7) ^ (rr & 7)) << 3;
    const __bf16* gA[4]; const __bf16* gB[4];
#pragma unroll
    for (int c = 0; c < 4; c++) {
        gA[c] = A + (size_t)(m0 + c * 32 + rr) * lda + csw;
        gB[c] = Bt + (size_t)(n0 + c * 32 + rr) * ldb + csw;
    }
    __bf16* lA = sAB + (w << 9);            // + db*8192 + c*2048
    __bf16* lB = sAB + 16384 + (w << 9);

    const int off0 = (lq * 8) ^ ((lr & 7) << 3);
    const int off1 = off0 ^ 32;
    const int arow = wm * 64 + lr;
    const int brow = wn * 64 + lr;

    f32x4 zero = {0.f, 0.f, 0.f, 0.f};
    f32x4 acc[4][4];
#pragma unroll
    for (int i = 0; i < 4; i++)
#pragma unroll
        for (int j = 0; j < 4; j++) acc[i][j] = zero;

    // prologue: stage K-tile 0 -> db0
#pragma unroll
    for (int c = 0; c < 4; c++) {
        g2l16(gA[c], lA + c * 2048);
        g2l16(gB[c], lB + c * 2048);
    }
    asm volatile("s_waitcnt vmcnt(0)" ::: "memory");
    __builtin_amdgcn_s_barrier();

    const int NT = Kp >> 6;
    for (int kt = 0; kt < NT; ++kt) {
        const int cur = kt & 1;
        const __bf16* pA = sAB + cur * 8192;
        const __bf16* pB = sAB + 16384 + cur * 8192;
        bf16x8 af[4][2], bfr[4][2];

        // ---- phase 1: issue next-tile stage; read all A + B[0..1]; 16 MFMA (j=0,1)
        if (kt + 1 < NT) {
            const int ko = (kt + 1) << 6;
            __bf16* dA = lA + (cur ^ 1) * 8192;
            __bf16* dB = lB + (cur ^ 1) * 8192;
#pragma unroll
            for (int c = 0; c < 4; c++) {
                g2l16(gA[c] + ko, dA + c * 2048);
                g2l16(gB[c] + ko, dB + c * 2048);
            }
        }
#pragma unroll
        for (int i = 0; i < 4; i++) {
            const __bf16* r = pA + (arow + i * 16) * 64;
            af[i][0] = *(const bf16x8*)(r + off0);
            af[i][1] = *(const bf16x8*)(r + off1);
        }
#pragma unroll
        for (int j = 0; j < 2; j++) {
            const __bf16* r = pB + (brow + j * 16) * 64;
            bfr[j][0] = *(const bf16x8*)(r + off0);
            bfr[j][1] = *(const bf16x8*)(r + off1);
        }
        __builtin_amdgcn_s_barrier();
        __builtin_amdgcn_s_setprio(1);
#pragma unroll
        for (int ks = 0; ks < 2; ks++)
#pragma unroll
            for (int i = 0; i < 4; i++)
#pragma unroll
                for (int j = 0; j < 2; j++)
                    acc[i][j] = __builtin_amdgcn_mfma_f32_16x16x32_bf16(af[i][ks], bfr[j][ks], acc[i][j], 0, 0, 0);
        __builtin_amdgcn_s_setprio(0);
        __builtin_amdgcn_s_barrier();

        // ---- phase 2: read B[2..3]; 16 MFMA (j=2,3); tile boundary
#pragma unroll
        for (int j = 2; j < 4; j++) {
            const __bf16* r = pB + (brow + j * 16) * 64;
            bfr[j][0] = *(const bf16x8*)(r + off0);
            bfr[j][1] = *(const bf16x8*)(r + off1);
        }
        __builtin_amdgcn_s_barrier();
        __builtin_amdgcn_s_setprio(1);
#pragma unroll
        for (int ks = 0; ks < 2; ks++)
#pragma unroll
            for (int i = 0; i < 4; i++)
#pragma unroll
                for (int j = 2; j < 4; j++)
                    acc[i][j] = __builtin_amdgcn_mfma_f32_16x16x32_bf16(af[i][ks], bfr[j][ks], acc[i][j], 0, 0, 0);
        __builtin_amdgcn_s_setprio(0);
        asm volatile("s_waitcnt vmcnt(0) lgkmcnt(0)" ::: "memory");
        __builtin_amdgcn_s_barrier();
    }

    // ---- epilogue
#pragma unroll
    for (int j = 0; j < 4; j++) {
        const int n = n0 + wn * 64 + j * 16 + lr;
        if (n < N) {
            const float bv = BIAS ? bias[n] : 0.f;
#pragma unroll
            for (int i = 0; i < 4; i++) {
#pragma unroll
                for (int r = 0; r < 4; r++) {
                    const int m = m0 + wm * 64 + i * 16 + lq * 4 + r;
                    float v = acc[i][j][r] + bv;
                    if (GELU) v = gelu_f(v);
                    if (SKIP) v += skip[(size_t)m * ldskip + n];
                    Cout[(size_t)m * ldc + n] = v;
                }
            }
        }
    }
}

// ---------------------------------------------------------------- RoPE in-place(q) + Kb bf16 + q/k norms
__global__ __launch_bounds__(256) void rope_k(
    float* __restrict__ QKV, const float* __restrict__ curv,
    float* __restrict__ qt, float* __restrict__ kt,
    __bf16* __restrict__ Kb, __bf16* __restrict__ Obf)
{
    int row = blockIdx.x;              // b*T + t
    int b = row >> 11, t = row & (TT - 1);
    int wv = threadIdx.x >> 6, d = threadIdx.x & 63;
    int j = d & 31;
    float fr = (float)t * powf(10000.0f, -(float)(2 * j) / 64.0f);
    float cv = cosf(fr), sv = sinf(fr);
    float sgn = (d < 32) ? sv : -sv;
    for (int h = wv; h < HH; h += 4) {
        float Kh = expf(curv[h]);
        float* base = QKV + (size_t)row * 3072 + h * 64;
        float q = base[d], k = base[1024 + d];
        float qp = __shfl_xor(q, 32);
        float kp = __shfl_xor(k, 32);
        float qr = q * cv + qp * sgn;
        float kr = k * cv + kp * sgn;
        base[d] = qr;                         // q roped in place (fp32 for hi/lo split)
        size_t oidx = ((size_t)(b * HH + h) * TT + t);
        Kb[oidx * 64 + d] = (__bf16)kr;       // roped k, bf16 head-major
        float sq = qr * qr, sk = kr * kr;
#pragma unroll
        for (int o = 32; o; o >>= 1) {
            sq += __shfl_xor(sq, o);
            sk += __shfl_xor(sk, o);
        }
        if (d == 0) {
            qt[oidx] = sqrtf(Kh + sq);
            kt[oidx] = sqrtf(Kh + sk);
        }
    }
    if (threadIdx.x < 48) Obf[(size_t)row * 1088 + 1040 + threadIdx.x] = (__bf16)0.f;
}

// ---------------------------------------------------------------- V transpose -> Vtb bf16 [bh][d][t] + vt norms
__global__ __launch_bounds__(256) void vtrans_k(
    const float* __restrict__ QKV, const float* __restrict__ curv,
    __bf16* __restrict__ Vtb, float* __restrict__ vt)
{
    __shared__ float sT[64 * 65];
    int bh = blockIdx.y; int h = bh & (HH - 1); int b = bh >> 4;
    int t0 = blockIdx.x * 64;
    int tid = threadIdx.x, w = tid >> 6, lane = tid & 63;
    float Kh = expf(curv[h]);
    const float* vbase = QKV + (size_t)(b * TT + t0) * 3072 + 2048 + h * 64;
#pragma unroll 4
    for (int i = 0; i < 16; i++) {
        int tr = w * 16 + i;
        float v = vbase[(size_t)tr * 3072 + lane];
        sT[lane * 65 + tr] = v;
        float s = v * v;
#pragma unroll
        for (int o = 32; o; o >>= 1) s += __shfl_xor(s, o);
        if (lane == 0) vt[(size_t)bh * TT + t0 + tr] = sqrtf(Kh + s);
    }
    __syncthreads();
    int d = tid >> 2, seg = tid & 3;
    const float* r = &sT[d * 65 + seg * 16];
    bf16x8 o0, o1;
#pragma unroll
    for (int i = 0; i < 8; i++) { o0[i] = (__bf16)r[i]; o1[i] = (__bf16)r[8 + i]; }
    __bf16* dst = Vtb + ((size_t)bh * 64 + d) * TT + t0 + seg * 16;
    *(bf16x8*)dst = o0;
    *(bf16x8*)(dst + 8) = o1;
}

// ---------------------------------------------------------------- MFMA flash hyperbolic attention (v7)
// v6 + per-block contiguous 64-row q-tile (no parked waves; heavy-first
// dispatch; bh -> XCD bh%8 keeps per-head K/V L2-local) + double-buffered
// K/V staging issued at phase top (latency hides under QK^T/score/PV).
__global__ __launch_bounds__(256, 3) void flash_k(
    const float* __restrict__ QKV,
    const __bf16* __restrict__ Kb, const __bf16* __restrict__ Vtb,
    const float* __restrict__ qt, const float* __restrict__ kt,
    const float* __restrict__ vt,
    const float* __restrict__ curv,
    __bf16* __restrict__ O)
{
    __shared__ __bf16 sK[2][4096];   // [buf][dgrp4][s=64][8 d]
    __shared__ __bf16 sVt[2][4096];  // [buf][tgrp4][d=64][8 t]
    __shared__ __bf16 sP[4 * 16 * 72];
    __shared__ float skt[2][64], svt[2][64];

    int bh = blockIdx.x; int h = bh & (HH - 1); int b = bh >> 4;
    int qti = 31 - (int)blockIdx.y;        // heavy blocks dispatch first
    int q0 = qti << 6;
    int NJ = qti + 1;
    float Kh = expf(curv[h]);
    float sqKh = sqrtf(Kh), msqK = -sqKh, invKh = 1.0f / Kh;
    const float* tok = QKV + (size_t)b * TT * 3072 + h * 64;  // roped q fp32
    const char* KbB = (const char*)Kb + (size_t)bh * TT * 128;
    const char* VtB = (const char*)Vtb + (size_t)bh * 64 * (TT * 2);
    const float* qtp = qt + (size_t)bh * TT;
    const float* ktp = kt + (size_t)bh * TT;
    const float* vtp = vt + (size_t)bh * TT;

    int tid = threadIdx.x;
    int w = tid >> 6, lane = tid & 63;
    int m = lane & 15, quad = lane >> 4;
    int myBase = q0 + 16 * w;              // all 4 waves share the same j-range
    __bf16* sPw = &sP[w * 16 * 72];

    // Q fragments (hi + lo bf16), A-layout: A[m][k=quad*8+j+32*ks]
    bf16x8 qhi[2], qlo[2];
    {
        const float* qrow = tok + (size_t)(myBase + m) * 3072;
#pragma unroll
        for (int ks = 0; ks < 2; ks++) {
            const float* s = qrow + quad * 8 + 32 * ks;
            float4 f0 = *(const float4*)s;
            float4 f1 = *(const float4*)(s + 4);
            float fa[8] = {f0.x, f0.y, f0.z, f0.w, f1.x, f1.y, f1.z, f1.w};
#pragma unroll
            for (int jj = 0; jj < 8; jj++) {
                __bf16 hv = (__bf16)fa[jj];
                qhi[ks][jj] = hv;
                qlo[ks][jj] = (__bf16)(fa[jj] - (float)hv);
            }
        }
    }
    float qtv[4]; int qg[4];
#pragma unroll
    for (int r = 0; r < 4; r++) { qg[r] = myBase + quad * 4 + r; qtv[r] = qtp[qg[r]]; }

    f32x4 zero = {0.f, 0.f, 0.f, 0.f};
    f32x4 accO[4];
#pragma unroll
    for (int nt = 0; nt < 4; nt++) accO[nt] = zero;
    float lsumr[4] = {}, o0r[4] = {};

    // ---- prologue: stage tile 0 -> buf 0
    {
        const char* kg = KbB + (size_t)lane * 128 + w * 16;
        char* sKb = (char*)&sK[0][0] + w * 1024;
        g2l16(kg,      sKb);
        g2l16(kg + 64, sKb + 4096);
        const char* vg = VtB + (size_t)lane * (TT * 2) + w * 16;
        char* sVb = (char*)&sVt[0][0] + w * 1024;
        g2l16(vg,      sVb);
        g2l16(vg + 64, sVb + 4096);
    }
    if (tid < 64) skt[0][tid] = ktp[tid];
    else if (tid < 128) svt[0][tid - 64] = vtp[tid - 64];
    __syncthreads();

    for (int j = 0; j < NJ; ++j) {
        int cur = j & 1;
        int sb = j << 6;
        // ---- issue next-tile stage EARLY (latency hides under compute) ----
        if (j + 1 < NJ) {
            int sb2 = sb + 64;
            const char* kg = KbB + (size_t)(sb2 + lane) * 128 + w * 16;
            char* sKb = (char*)&sK[cur ^ 1][0] + w * 1024;
            g2l16(kg,      sKb);
            g2l16(kg + 64, sKb + 4096);
            const char* vg = VtB + (size_t)lane * (TT * 2) + sb2 * 2 + w * 16;
            char* sVb = (char*)&sVt[cur ^ 1][0] + w * 1024;
            g2l16(vg,      sVb);
            g2l16(vg + 64, sVb + 4096);
            if (tid < 64) skt[cur ^ 1][tid] = ktp[sb2 + tid];
            else if (tid < 128) svt[cur ^ 1][tid - 64] = vtp[sb2 + tid - 64];
        }

        // ---- QK^T: S[16 x 64] ----
        f32x4 accS[4];
#pragma unroll
        for (int nt = 0; nt < 4; nt++) accS[nt] = zero;
#pragma unroll
        for (int nt = 0; nt < 4; nt++) {
#pragma unroll
            for (int ksp = 0; ksp < 2; ksp++) {
                bf16x8 bk = *(const bf16x8*)&sK[cur][((ksp * 4 + quad) * 64 + nt * 16 + m) * 8];
                accS[nt] = __builtin_amdgcn_mfma_f32_16x16x32_bf16(qhi[ksp], bk, accS[nt], 0, 0, 0);
                accS[nt] = __builtin_amdgcn_mfma_f32_16x16x32_bf16(qlo[ksp], bk, accS[nt], 0, 0, 0);
            }
        }
        // ---- score epilogue: hyperbolic logit -> p, raw transcendentals ----
#pragma unroll
        for (int nt = 0; nt < 4; nt++) {
            int col = nt * 16 + m;
            int sglob = sb + col;
            float ktv = skt[cur][col], vtv = svt[cur][col];
#pragma unroll
            for (int r = 0; r < 4; r++) {
                float dot = accS[nt][r];
                float rdiff = fmaf(qtv[r], ktv, -dot);          // qt*kt - q.k
                float ratio = fmaxf(rdiff * invKh, 1.0f + 1e-7f);
                float y = ratio + fsqrt_(fmaf(ratio, ratio, -1.0f));
                float pv = fexp2(msqK * flog2(y));              // exp(-sqrt(K)*acosh)
                float p = (sglob <= qg[r]) ? pv : 0.0f;
                lsumr[r] += p;
                o0r[r] = fmaf(p, vtv, o0r[r]);
                sPw[(quad * 4 + r) * 72 + col] = (__bf16)p;
            }
        }
        __asm__ volatile("s_waitcnt lgkmcnt(0)" ::: "memory");
        // ---- PV: O += P @ V ----
#pragma unroll
        for (int ksp = 0; ksp < 2; ksp++) {
            bf16x8 aP = *(const bf16x8*)&sPw[m * 72 + ksp * 32 + quad * 8];
#pragma unroll
            for (int nt = 0; nt < 4; nt++) {
                bf16x8 bV = *(const bf16x8*)&sVt[cur][((ksp * 4 + quad) * 64 + nt * 16 + m) * 8];
                accO[nt] = __builtin_amdgcn_mfma_f32_16x16x32_bf16(aP, bV, accO[nt], 0, 0, 0);
            }
        }
        __syncthreads();   // drains vmcnt+lgkm: next-tile staging complete, buf reuse safe
    }

    // ---- final: reduce lsum/o0 over the 16 col-lanes, normalize, write ----
#pragma unroll
    for (int r = 0; r < 4; r++) {
#pragma unroll
        for (int off = 1; off < 16; off <<= 1) {
            lsumr[r] += __shfl_xor(lsumr[r], off);
            o0r[r]   += __shfl_xor(o0r[r], off);
        }
    }
#pragma unroll
    for (int r = 0; r < 4; r++) {
        float inv = frcp_(lsumr[r]);
        float o0f = o0r[r] * inv;
        float ov[4]; float part = 0.f;
#pragma unroll
        for (int nt = 0; nt < 4; nt++) { float t = accO[nt][r] * inv; ov[nt] = t; part += t * t; }
        part += __shfl_xor(part, 1);
        part += __shfl_xor(part, 2);
        part += __shfl_xor(part, 4);
        part += __shfl_xor(part, 8);
        float scale = sqKh * frsq_(fmaxf(o0f * o0f - part, 1e-12f));
        size_t orow = (size_t)(b * TT + qg[r]) * 1088 + h * 65;
        if (m == 0) O[orow] = (__bf16)(o0f * scale);
#pragma unroll
        for (int nt = 0; nt < 4; nt++) O[orow + 1 + nt * 16 + m] = (__bf16)(ov[nt] * scale);
    }
}

// ---------------------------------------------------------------- launch
extern "C" void kernel_launch(void* const* d_in, const int* in_sizes, int n_in,
                              void* d_out, int out_size, void* d_ws, size_t ws_size,
                              hipStream_t stream) {
    const float* x    = (const float*)d_in[0];
    const float* bc   = (const float*)d_in[1];
    const float* mc   = (const float*)d_in[2];
    const float* ac   = (const float*)d_in[3];
    const float* w_qkv = (const float*)d_in[4];
    const float* w_ap  = (const float*)d_in[5];
    const float* b_ap  = (const float*)d_in[6];
    const float* w_me  = (const float*)d_in[7];
    const float* b_me  = (const float*)d_in[8];
    const float* w_ms  = (const float*)d_in[9];
    const float* b_ms  = (const float*)d_in[10];
    const float* lnw  = (const float*)d_in[11];
    const float* lnb  = (const float*)d_in[12];
    float* out = (float*)d_out;
    float* ws  = (float*)d_ws;

    // workspace (floats), total ~96.5 MB.
    float* R      = ws;
    float* qkvbuf = R;                             // M*3072 fp32 (dead after flash)
    float* X2     = R;                             // M*1024 fp32 (written step 5)
    __bf16* h_bf  = (__bf16*)(R + 4194304);        // M*4224 bf16 -> ends 12,845,056
    float* p      = R + 12845056;
    __bf16* ln_bf = (__bf16*)p;  p += 2228224;     // M*1088 bf16
    __bf16* o_bf  = (__bf16*)p;  p += 2228224;     // M*1088 bf16
    __bf16* qkvT  = (__bf16*)p;  p += 1671168;     // 3072*1088 bf16
    __bf16* apT   = (__bf16*)p;  p += 557056;      // 1024*1088 bf16
    float*  meT_f = p;           p += 2229856;     // 4099*1088 bf16 (after flash)
    float*  msT_f = p;           p += 2162688;     // 1024*4224 bf16 (after flash)
    float* Qt = p;               p += 2 * HH * TT;
    float* Kt = p;               p += 2 * HH * TT;
    float* Vt = p;
    __bf16* meT = (__bf16*)meT_f;
    __bf16* msT = (__bf16*)msT_f;
    __bf16* Kb  = (__bf16*)meT_f;   // 32*2048*64 bf16 <= meT slot; dead before wt_k(meT)
    __bf16* Vtb = (__bf16*)msT_f;   // same size      <= msT slot; dead before wt_k(msT)

    // 0. weight transposes needed before flash (zero-filled past K)
    wt_k<<<dim3(34, 96),  256, 0, stream>>>(w_qkv, 1025, 3072, qkvT, 1088);
    wt_k<<<dim3(34, 32),  256, 0, stream>>>(w_ap,  1040, 1024, apT,  1088);

    // 1. ln1 = block_norm(project(x)) -> bf16 (stride 1088, zero pad)
    block_norm_bf_k<<<MM, 256, 0, stream>>>(x, 1024, ln_bf, 1088, lnw, lnb, bc);
    // 2. qkv = ln1 @ w_qkv -> fp32 (M,3072)   [256^2, XCD-chunked]
    mgemm256_k<false, false, false><<<dim3(12, 16), 512, 0, stream>>>(
        ln_bf, 1088, qkvT, 1088, 3072, nullptr, qkvbuf, 3072, 3072, 1088);
    // 3a. RoPE (q in place fp32, Kb bf16) + q/k norms + o_bf pad (cols 1040..1087)
    rope_k<<<MM, 256, 0, stream>>>(qkvbuf, ac, Qt, Kt, Kb, o_bf);
    // 3b. V transpose -> Vtb bf16 + v norms
    vtrans_k<<<dim3(32, 32), 256, 0, stream>>>(qkvbuf, ac, Vtb, Vt);
    // 4. MFMA flash attention -> o_t bf16 (M,1088)
    flash_k<<<dim3(2 * HH, 32), 256, 0, stream>>>(qkvbuf, Kb, Vtb, Qt, Kt, Vt, ac, o_bf);
    // 0b. remaining weight transposes (into the slots Kb/Vtb just vacated)
    wt_k<<<dim3(34, 129), 256, 0, stream>>>(w_me,  1025, 4099, meT, 1088);
    wt_k<<<dim3(132, 32), 256, 0, stream>>>(w_ms,  4100, 1024, msT, 4224);
    // 5. lx2[...,1:] = x + o_t @ w_attn_proj + b -> X2 fp32   [128^2 pipelined]
    mgemm128_k<true, false, true><<<dim3(256), 256, 0, stream>>>(
        o_bf, 1088, apT, 1088, b_ap, x, 1024, X2, 1024, 1024, 1088);
    // 6. ln2 = block_norm(lx2) -> bf16
    block_norm_bf_k<<<MM, 256, 0, stream>>>(X2, 1024, ln_bf, 1088, lnw, lnb, bc);
    // 7. h[1..4096] = gelu(ln2 @ w_mlp_expand + b) -> bf16   [256^2, XCD-chunked, exact 16x16]
    mgemm256_k<true, true, true><<<dim3(16, 16), 512, 0, stream>>>(
        ln_bf, 1088, meT, 1088, 4099, b_me, (void*)(h_bf + 1), 4224, 4099, 1088);
    // 8. h cols 4097..4099 (ragged tail vs meT rows 4096..4098) + x0 + pad
    row_x0_tail_k<<<MM, 256, 0, stream>>>(h_bf, ln_bf, meT, b_me, mc);
    // 9. out[...,1:] = lx2[...,1:] + h @ w_mlp_shrink + b   [128^2 pipelined]
    mgemm128_k<true, false, true><<<dim3(256), 256, 0, stream>>>(
        h_bf, 4224, msT, 4224, b_ms, X2, 1024, out + 1, 1025, 1024, 4224);
    // 10. out[...,0]
    row_x0_k<<<MM, 256, 0, stream>>>(out, 1025, 1024, bc);
}